// Round 1
// baseline (931.177 us; speedup 1.0000x reference)
//
#include <hip/hip_runtime.h>

typedef __attribute__((ext_vector_type(4))) float f32x4;
typedef __attribute__((ext_vector_type(8))) __bf16 bf16x8;

#define T_DIM 2048
#define B_DIM 4
#define C_DIM 1024
#define H_N 8
#define D_H 128
#define M_ROWS 8192   // B*T

// ---------------- RoPE cos/sin table: [T][64] float2 ----------------
__global__ void rope_table_k(float2* __restrict__ tab) {
    int idx = blockIdx.x * 256 + threadIdx.x;
    if (idx >= T_DIM * 64) return;
    int t = idx >> 6, i = idx & 63;
    // inv_freq = 10000^(-(2i)/128)
    float freq = expf(-(2.0f * (float)i / 128.0f) * 9.210340371976184f);
    float a = (float)t * freq;
    tab[idx] = make_float2(cosf(a), sinf(a));
}

// ---------------- beta / mix heads: x@Wb+bb (sigmoid), x@Wm+bm (softmax over K=2) ----
__global__ __launch_bounds__(256) void betamix_k(
    const float* __restrict__ x,
    const float* __restrict__ Wb, const float* __restrict__ bb,
    const float* __restrict__ Wm, const float* __restrict__ bm,
    float* __restrict__ beta, float* __restrict__ mix) {
    // 256 threads = 8 rows x 32 cols (c<16 -> beta col c ; c>=16 -> mix col c-16)
    int row = blockIdx.x * 8 + (threadIdx.x >> 5);
    int c = threadIdx.x & 31;
    bool is_mix = c >= 16;
    int col = c & 15;
    const float* W = is_mix ? Wm : Wb;
    const float* xr = x + (size_t)row * C_DIM;
    float acc = 0.f;
    for (int k = 0; k < C_DIM; k += 4) {
        f32x4 xv = *(const f32x4*)(xr + k);
        acc += xv.x * W[(k + 0) * 16 + col];
        acc += xv.y * W[(k + 1) * 16 + col];
        acc += xv.z * W[(k + 2) * 16 + col];
        acc += xv.w * W[(k + 3) * 16 + col];
    }
    acc += is_mix ? bm[col] : bb[col];
    if (!is_mix) {
        beta[(size_t)row * 16 + col] = 1.f / (1.f + expf(-acc));
    } else {
        // softmax over the (even,odd) K-pair; partner lane is lane^1 (same 32-lane half)
        float other = __shfl_xor(acc, 1);
        float mx = fmaxf(acc, other);
        float e = expf(acc - mx), eo = expf(other - mx);
        mix[(size_t)row * 16 + col] = e / (e + eo);
    }
}

// ---------------- bf16 MFMA GEMM: C = A(fp32,MxK) @ B(fp32,KxN) [+bias] [RoPE epilogue] ---
// 128x128 tile, BK=32, 256 threads = 4 waves (2x2), each wave 64x64 = 4x4 MFMA frags.
// A/B staged fp32->bf16 into k-contiguous LDS tiles; fragments use the SAME k-slot
// bijection for A and B (k = 8*(lane/16)+e), so the result is layout-convention-proof.
#define BKG 32
__global__ __launch_bounds__(256) void gemm_k(
    const float* __restrict__ A, const float* __restrict__ Bm,
    float* __restrict__ C, int M, int N, int K,
    const float2* __restrict__ rope_tab,  // null = no rope
    const float* __restrict__ bias) {     // null = no bias
    __shared__ __bf16 As[128][BKG + 8];   // stride 40 bf16 = 80B (16B-aligned rows)
    __shared__ __bf16 Bs[128][BKG + 8];   // Bs[n][k] (transposed tile)

    int tid = threadIdx.x;
    int nTilesN = N / 128;
    int bm_i = blockIdx.x / nTilesN, bn_i = blockIdx.x % nTilesN;
    int m_base = bm_i * 128, n_base = bn_i * 128;
    int wave = tid >> 6, lane = tid & 63;
    int wm = (wave >> 1) * 64, wn = (wave & 1) * 64;
    int lrow = lane & 15, lgrp = lane >> 4;

    f32x4 acc[4][4] = {};

    for (int k0 = 0; k0 < K; k0 += BKG) {
        __syncthreads();
        // stage A: 128x32 fp32 -> bf16, coalesced (8 tids per row)
        #pragma unroll
        for (int it = 0; it < 4; ++it) {
            int f = tid + it * 256;            // 1024 float4
            int r = f >> 3, c4 = (f & 7) * 4;
            f32x4 v = *(const f32x4*)(A + (size_t)(m_base + r) * K + k0 + c4);
            __bf16* d = &As[r][c4];
            d[0] = (__bf16)v.x; d[1] = (__bf16)v.y; d[2] = (__bf16)v.z; d[3] = (__bf16)v.w;
        }
        // stage B transposed: thread reads 4 floats along n of row k0+kr, writes b16s
        // (lanes vary kr -> contiguous-k LDS writes, conflict-free; weights are L2-hot)
        #pragma unroll
        for (int it = 0; it < 4; ++it) {
            int f = tid + it * 256;
            int kr = f & 31, n4 = (f >> 5) * 4;
            f32x4 v = *(const f32x4*)(Bm + (size_t)(k0 + kr) * N + n_base + n4);
            Bs[n4 + 0][kr] = (__bf16)v.x;
            Bs[n4 + 1][kr] = (__bf16)v.y;
            Bs[n4 + 2][kr] = (__bf16)v.z;
            Bs[n4 + 3][kr] = (__bf16)v.w;
        }
        __syncthreads();

        bf16x8 af[4], bf[4];
        #pragma unroll
        for (int i = 0; i < 4; ++i) {
            af[i] = *(const bf16x8*)&As[wm + i * 16 + lrow][lgrp * 8];
            bf[i] = *(const bf16x8*)&Bs[wn + i * 16 + lrow][lgrp * 8];
        }
        #pragma unroll
        for (int i = 0; i < 4; ++i)
            #pragma unroll
            for (int j = 0; j < 4; ++j)
                acc[i][j] = __builtin_amdgcn_mfma_f32_16x16x32_bf16(af[i], bf[j], acc[i][j], 0, 0, 0);
    }

    // epilogue: C/D layout (verified): row = 4*(lane/16)+reg, col = lane&15
    bool do_rope = rope_tab != nullptr;
    #pragma unroll
    for (int i = 0; i < 4; ++i) {
        #pragma unroll
        for (int j = 0; j < 4; ++j) {
            #pragma unroll
            for (int r = 0; r < 4; ++r) {
                int grow = m_base + wm + i * 16 + (lgrp << 2) + r;
                int gcol = n_base + wn + j * 16 + lrow;
                float val = acc[i][j][r];
                if (do_rope) {
                    float partner = __shfl_xor(val, 1);  // col parity == lane parity
                    int t = grow & (T_DIM - 1);
                    int ii = (gcol & 127) >> 1;
                    float2 cs = rope_tab[t * 64 + ii];
                    val = (gcol & 1) ? (partner * cs.y + val * cs.x)
                                     : (val * cs.x - partner * cs.y);
                }
                if (bias) val += bias[gcol];
                C[(size_t)grow * N + gcol] = val;
            }
        }
    }
}

// ---------------- sequential scan over T --------------------------------
// grid (8 e-chunks, H, B) = 256 blocks; 256 threads = 16 e x 16 d-groups.
// Each thread owns S[k=0..1][8 d] in registers. 32-step time tiles staged in LDS.
// Mask folded at staging: beta->1, mix->0, v->0 when mask==0.
__global__ __launch_bounds__(256) void scan_k(
    const float* __restrict__ qg, const float* __restrict__ kg, const float* __restrict__ vg,
    const float* __restrict__ beta, const float* __restrict__ mix,
    const int* __restrict__ mask, float* __restrict__ y) {
    __shared__ float ks[32][128];
    __shared__ float qs[32][128];
    __shared__ float vs[32][16];
    __shared__ f32x4 bms[32];

    int tid = threadIdx.x;
    int e0 = blockIdx.x * 16;
    int h = blockIdx.y, b = blockIdx.z;
    int e = tid >> 4, dg = tid & 15, d0 = dg * 8;
    size_t rowbase = (size_t)b * T_DIM;

    float S0[8] = {0,0,0,0,0,0,0,0};
    float S1[8] = {0,0,0,0,0,0,0,0};

    for (int t0 = 0; t0 < T_DIM; t0 += 32) {
        __syncthreads();
        #pragma unroll
        for (int it = 0; it < 4; ++it) {
            int f = tid + it * 256;          // 1024 float4 per array
            int s = f >> 5, c4 = (f & 31) * 4;
            size_t g = (rowbase + t0 + s) * C_DIM + h * D_H + c4;
            *(f32x4*)&ks[s][c4] = *(const f32x4*)(kg + g);
            *(f32x4*)&qs[s][c4] = *(const f32x4*)(qg + g);
        }
        if (tid < 128) {
            int s = tid >> 2, c4 = (tid & 3) * 4;
            int mk = mask[rowbase + t0 + s];
            f32x4 vv = *(const f32x4*)(vg + (rowbase + t0 + s) * C_DIM + h * D_H + e0 + c4);
            float mf = mk ? 1.f : 0.f;
            vv = vv * mf;
            *(f32x4*)&vs[s][c4] = vv;
        }
        if (tid < 32) {
            int s = tid;
            size_t r16 = (rowbase + t0 + s) * 16 + h * 2;
            int mk = mask[rowbase + t0 + s];
            f32x4 w;
            w.x = mk ? beta[r16]     : 1.f;
            w.y = mk ? beta[r16 + 1] : 1.f;
            w.z = mk ? mix[r16]      : 0.f;
            w.w = mk ? mix[r16 + 1]  : 0.f;
            bms[s] = w;
        }
        __syncthreads();

        #pragma unroll 2
        for (int s = 0; s < 32; ++s) {
            f32x4 ka = *(f32x4*)&ks[s][d0], kb = *(f32x4*)&ks[s][d0 + 4];
            f32x4 qa = *(f32x4*)&qs[s][d0], qb = *(f32x4*)&qs[s][d0 + 4];
            float vv = vs[s][e];
            f32x4 w = bms[s];
            float py0 = 0.f, py1 = 0.f;
            #pragma unroll
            for (int j = 0; j < 4; ++j) {
                float kv = ka[j] * vv;
                S0[j] = w.x * S0[j] + kv;
                S1[j] = w.y * S1[j] + kv;
                py0 += qa[j] * S0[j];
                py1 += qa[j] * S1[j];
                float kv2 = kb[j] * vv;
                S0[j + 4] = w.x * S0[j + 4] + kv2;
                S1[j + 4] = w.y * S1[j + 4] + kv2;
                py0 += qb[j] * S0[j + 4];
                py1 += qb[j] * S1[j + 4];
            }
            float yv = w.z * py0 + w.w * py1;
            yv += __shfl_xor(yv, 1);
            yv += __shfl_xor(yv, 2);
            yv += __shfl_xor(yv, 4);
            yv += __shfl_xor(yv, 8);
            if (dg == 0)
                y[(rowbase + t0 + s) * C_DIM + h * D_H + e0 + e] = yv;
        }
    }
}

extern "C" void kernel_launch(void* const* d_in, const int* in_sizes, int n_in,
                              void* d_out, int out_size, void* d_ws, size_t ws_size,
                              hipStream_t stream) {
    const float* x    = (const float*)d_in[0];
    const int*   mask = (const int*)d_in[1];
    const float* Wq   = (const float*)d_in[2];
    const float* Wk   = (const float*)d_in[3];
    const float* Wv   = (const float*)d_in[4];
    const float* Wb   = (const float*)d_in[5];
    const float* bb   = (const float*)d_in[6];
    const float* Wm   = (const float*)d_in[7];
    const float* bm   = (const float*)d_in[8];
    const float* Wo   = (const float*)d_in[9];
    const float* bo   = (const float*)d_in[10];
    float* out = (float*)d_out;

    const size_t MC = (size_t)M_ROWS * C_DIM;   // 8388608
    float* ws   = (float*)d_ws;
    float* q    = ws;
    float* k    = q + MC;
    float* v    = k + MC;
    float* y    = v + MC;
    float* beta = y + MC;            // 8192*16
    float* mix  = beta + M_ROWS * 16;
    float2* rope = (float2*)(mix + M_ROWS * 16);  // [T][64]

    // 1) rope table
    rope_table_k<<<dim3((T_DIM * 64) / 256), dim3(256), 0, stream>>>(rope);
    // 2) beta / mix
    betamix_k<<<dim3(M_ROWS / 8), dim3(256), 0, stream>>>(x, Wb, bb, Wm, bm, beta, mix);
    // 3) q, k, v projections (rope fused for q,k)
    dim3 ggrid((M_ROWS / 128) * (C_DIM / 128));
    gemm_k<<<ggrid, dim3(256), 0, stream>>>(x, Wq, q, M_ROWS, C_DIM, C_DIM, rope, nullptr);
    gemm_k<<<ggrid, dim3(256), 0, stream>>>(x, Wk, k, M_ROWS, C_DIM, C_DIM, rope, nullptr);
    gemm_k<<<ggrid, dim3(256), 0, stream>>>(x, Wv, v, M_ROWS, C_DIM, C_DIM, nullptr, nullptr);
    // 4) scan
    scan_k<<<dim3(8, H_N, B_DIM), dim3(256), 0, stream>>>(q, k, v, beta, mix, mask, y);
    // 5) output projection + bias
    gemm_k<<<ggrid, dim3(256), 0, stream>>>(y, Wo, out, M_ROWS, C_DIM, C_DIM, nullptr, bo);
}

// Round 2
// 721.759 us; speedup vs baseline: 1.2901x; 1.2901x over previous
//
#include <hip/hip_runtime.h>

typedef __attribute__((ext_vector_type(4))) float f32x4;
typedef __attribute__((ext_vector_type(8))) __bf16 bf16x8;

#define T_DIM 2048
#define B_DIM 4
#define C_DIM 1024
#define H_N 8
#define D_H 128
#define M_ROWS 8192   // B*T

// ---------------- RoPE cos/sin table: [T][64] float2 ----------------
__global__ void rope_table_k(float2* __restrict__ tab) {
    int idx = blockIdx.x * 256 + threadIdx.x;
    if (idx >= T_DIM * 64) return;
    int t = idx >> 6, i = idx & 63;
    // inv_freq = 10000^(-(2i)/128)
    float freq = expf(-(2.0f * (float)i / 128.0f) * 9.210340371976184f);
    float a = (float)t * freq;
    tab[idx] = make_float2(cosf(a), sinf(a));
}

// ---------------- beta / mix heads: x@Wb+bb (sigmoid), x@Wm+bm (softmax over K=2) ----
__global__ __launch_bounds__(256) void betamix_k(
    const float* __restrict__ x,
    const float* __restrict__ Wb, const float* __restrict__ bb,
    const float* __restrict__ Wm, const float* __restrict__ bm,
    float* __restrict__ beta, float* __restrict__ mix) {
    // 256 threads = 8 rows x 32 cols (c<16 -> beta col c ; c>=16 -> mix col c-16)
    int row = blockIdx.x * 8 + (threadIdx.x >> 5);
    int c = threadIdx.x & 31;
    bool is_mix = c >= 16;
    int col = c & 15;
    const float* W = is_mix ? Wm : Wb;
    const float* xr = x + (size_t)row * C_DIM;
    float acc = 0.f;
    for (int k = 0; k < C_DIM; k += 4) {
        f32x4 xv = *(const f32x4*)(xr + k);
        acc += xv.x * W[(k + 0) * 16 + col];
        acc += xv.y * W[(k + 1) * 16 + col];
        acc += xv.z * W[(k + 2) * 16 + col];
        acc += xv.w * W[(k + 3) * 16 + col];
    }
    acc += is_mix ? bm[col] : bb[col];
    if (!is_mix) {
        beta[(size_t)row * 16 + col] = 1.f / (1.f + expf(-acc));
    } else {
        // softmax over the (even,odd) K-pair; partner lane is lane^1 (same 32-lane half)
        float other = __shfl_xor(acc, 1);
        float mx = fmaxf(acc, other);
        float e = expf(acc - mx), eo = expf(other - mx);
        mix[(size_t)row * 16 + col] = e / (e + eo);
    }
}

// ---------------- bf16 MFMA GEMM: C = A(fp32,MxK) @ B(fp32,KxN) [+bias] [RoPE epilogue] ---
#define BKG 32
__global__ __launch_bounds__(256) void gemm_k(
    const float* __restrict__ A, const float* __restrict__ Bm,
    float* __restrict__ C, int M, int N, int K,
    const float2* __restrict__ rope_tab,  // null = no rope
    const float* __restrict__ bias) {     // null = no bias
    __shared__ __bf16 As[128][BKG + 8];   // stride 40 bf16 = 80B (16B-aligned rows)
    __shared__ __bf16 Bs[128][BKG + 8];   // Bs[n][k] (transposed tile)

    int tid = threadIdx.x;
    int nTilesN = N / 128;
    int bm_i = blockIdx.x / nTilesN, bn_i = blockIdx.x % nTilesN;
    int m_base = bm_i * 128, n_base = bn_i * 128;
    int wave = tid >> 6, lane = tid & 63;
    int wm = (wave >> 1) * 64, wn = (wave & 1) * 64;
    int lrow = lane & 15, lgrp = lane >> 4;

    f32x4 acc[4][4] = {};

    for (int k0 = 0; k0 < K; k0 += BKG) {
        __syncthreads();
        #pragma unroll
        for (int it = 0; it < 4; ++it) {
            int f = tid + it * 256;            // 1024 float4
            int r = f >> 3, c4 = (f & 7) * 4;
            f32x4 v = *(const f32x4*)(A + (size_t)(m_base + r) * K + k0 + c4);
            __bf16* d = &As[r][c4];
            d[0] = (__bf16)v.x; d[1] = (__bf16)v.y; d[2] = (__bf16)v.z; d[3] = (__bf16)v.w;
        }
        #pragma unroll
        for (int it = 0; it < 4; ++it) {
            int f = tid + it * 256;
            int kr = f & 31, n4 = (f >> 5) * 4;
            f32x4 v = *(const f32x4*)(Bm + (size_t)(k0 + kr) * N + n_base + n4);
            Bs[n4 + 0][kr] = (__bf16)v.x;
            Bs[n4 + 1][kr] = (__bf16)v.y;
            Bs[n4 + 2][kr] = (__bf16)v.z;
            Bs[n4 + 3][kr] = (__bf16)v.w;
        }
        __syncthreads();

        bf16x8 af[4], bf[4];
        #pragma unroll
        for (int i = 0; i < 4; ++i) {
            af[i] = *(const bf16x8*)&As[wm + i * 16 + lrow][lgrp * 8];
            bf[i] = *(const bf16x8*)&Bs[wn + i * 16 + lrow][lgrp * 8];
        }
        #pragma unroll
        for (int i = 0; i < 4; ++i)
            #pragma unroll
            for (int j = 0; j < 4; ++j)
                acc[i][j] = __builtin_amdgcn_mfma_f32_16x16x32_bf16(af[i], bf[j], acc[i][j], 0, 0, 0);
    }

    bool do_rope = rope_tab != nullptr;
    #pragma unroll
    for (int i = 0; i < 4; ++i) {
        #pragma unroll
        for (int j = 0; j < 4; ++j) {
            #pragma unroll
            for (int r = 0; r < 4; ++r) {
                int grow = m_base + wm + i * 16 + (lgrp << 2) + r;
                int gcol = n_base + wn + j * 16 + lrow;
                float val = acc[i][j][r];
                if (do_rope) {
                    float partner = __shfl_xor(val, 1);  // col parity == lane parity
                    int t = grow & (T_DIM - 1);
                    int ii = (gcol & 127) >> 1;
                    float2 cs = rope_tab[t * 64 + ii];
                    val = (gcol & 1) ? (partner * cs.y + val * cs.x)
                                     : (val * cs.x - partner * cs.y);
                }
                if (bias) val += bias[gcol];
                C[(size_t)grow * N + gcol] = val;
            }
        }
    }
}

// ---------------- sequential scan over T --------------------------------
// grid (16 e-chunks, H, B) = 512 blocks; 256 threads = 8 e x 32 dg (4 d each).
// Per thread: S[k=0..1][4 d] in registers. 32-step time tiles staged in LDS.
// Per-step reduction: 2 shuffles (4 lanes) + conflict-free LDS partial write;
// batched tile-end reduction over the 8 dg-quads (padded part rows -> 2-way/free).
#define SCAN_TS 32
__global__ __launch_bounds__(256) void scan_k(
    const float* __restrict__ qg, const float* __restrict__ kg, const float* __restrict__ vg,
    const float* __restrict__ beta, const float* __restrict__ mix,
    const int* __restrict__ mask, float* __restrict__ y) {
    __shared__ float ks[SCAN_TS][128];
    __shared__ float qs[SCAN_TS][128];
    __shared__ float vs[SCAN_TS][8];
    __shared__ f32x4 bms[SCAN_TS];
    __shared__ float part[SCAN_TS][65];   // [s][e*8 + dg/4], padded: reduce reads 2-way

    int tid = threadIdx.x;
    int e0 = blockIdx.x * 8;
    int h = blockIdx.y, b = blockIdx.z;
    int e = tid >> 5, dg = tid & 31, d0 = dg * 4;
    size_t rowbase = (size_t)b * T_DIM;

    f32x4 S0 = {0, 0, 0, 0};
    f32x4 S1 = {0, 0, 0, 0};

    // reduce-phase mapping: thread p -> (s, e) pair
    int rs = tid >> 3, re = tid & 7;

    for (int t0 = 0; t0 < T_DIM; t0 += SCAN_TS) {
        __syncthreads();
        // stage k,q: 32 rows x 128 floats = 1024 f32x4 per array
        #pragma unroll
        for (int it = 0; it < 4; ++it) {
            int f = tid + it * 256;
            int s = f >> 5, c4 = (f & 31) * 4;
            size_t g = (rowbase + t0 + s) * C_DIM + h * D_H + c4;
            *(f32x4*)&ks[s][c4] = *(const f32x4*)(kg + g);
            *(f32x4*)&qs[s][c4] = *(const f32x4*)(qg + g);
        }
        // stage v (masked): 32 s x 8 e
        if (tid < 64) {
            int s = tid >> 1, c4 = (tid & 1) * 4;
            int mk = mask[rowbase + t0 + s];
            f32x4 vv = *(const f32x4*)(vg + (rowbase + t0 + s) * C_DIM + h * D_H + e0 + c4);
            float mf = mk ? 1.f : 0.f;
            vv = vv * mf;
            *(f32x4*)&vs[s][c4] = vv;
        } else if (tid < 96) {
            int s = tid - 64;
            size_t r16 = (rowbase + t0 + s) * 16 + h * 2;
            int mk = mask[rowbase + t0 + s];
            f32x4 w;
            w.x = mk ? beta[r16]     : 1.f;
            w.y = mk ? beta[r16 + 1] : 1.f;
            w.z = mk ? mix[r16]      : 0.f;
            w.w = mk ? mix[r16 + 1]  : 0.f;
            bms[s] = w;
        }
        __syncthreads();

        #pragma unroll
        for (int s = 0; s < SCAN_TS; ++s) {
            f32x4 ka = *(f32x4*)&ks[s][d0];
            f32x4 qa = *(f32x4*)&qs[s][d0];
            float vv = vs[s][e];
            f32x4 w = bms[s];
            float py0 = 0.f, py1 = 0.f;
            #pragma unroll
            for (int j = 0; j < 4; ++j) {
                float kv = ka[j] * vv;
                S0[j] = w.x * S0[j] + kv;
                S1[j] = w.y * S1[j] + kv;
                py0 += qa[j] * S0[j];
                py1 += qa[j] * S1[j];
            }
            float yv = w.z * py0 + w.w * py1;
            yv += __shfl_xor(yv, 1);
            yv += __shfl_xor(yv, 2);
            if ((dg & 3) == 0)
                part[s][e * 8 + (dg >> 2)] = yv;
        }
        __syncthreads();

        // tile-end reduce: thread p = (s = tid>>3, e = tid&7) sums 8 dg-quads
        {
            const float* pr = &part[rs][re * 8];
            float acc = 0.f;
            #pragma unroll
            for (int j = 0; j < 8; ++j) acc += pr[j];
            y[(rowbase + t0 + rs) * C_DIM + h * D_H + e0 + re] = acc;
        }
    }
}

extern "C" void kernel_launch(void* const* d_in, const int* in_sizes, int n_in,
                              void* d_out, int out_size, void* d_ws, size_t ws_size,
                              hipStream_t stream) {
    const float* x    = (const float*)d_in[0];
    const int*   mask = (const int*)d_in[1];
    const float* Wq   = (const float*)d_in[2];
    const float* Wk   = (const float*)d_in[3];
    const float* Wv   = (const float*)d_in[4];
    const float* Wb   = (const float*)d_in[5];
    const float* bb   = (const float*)d_in[6];
    const float* Wm   = (const float*)d_in[7];
    const float* bm   = (const float*)d_in[8];
    const float* Wo   = (const float*)d_in[9];
    const float* bo   = (const float*)d_in[10];
    float* out = (float*)d_out;

    const size_t MC = (size_t)M_ROWS * C_DIM;   // 8388608
    float* ws   = (float*)d_ws;
    float* q    = ws;
    float* k    = q + MC;
    float* v    = k + MC;
    float* y    = v + MC;
    float* beta = y + MC;            // 8192*16
    float* mix  = beta + M_ROWS * 16;
    float2* rope = (float2*)(mix + M_ROWS * 16);  // [T][64]

    // 1) rope table
    rope_table_k<<<dim3((T_DIM * 64) / 256), dim3(256), 0, stream>>>(rope);
    // 2) beta / mix
    betamix_k<<<dim3(M_ROWS / 8), dim3(256), 0, stream>>>(x, Wb, bb, Wm, bm, beta, mix);
    // 3) q, k, v projections (rope fused for q,k)
    dim3 ggrid((M_ROWS / 128) * (C_DIM / 128));
    gemm_k<<<ggrid, dim3(256), 0, stream>>>(x, Wq, q, M_ROWS, C_DIM, C_DIM, rope, nullptr);
    gemm_k<<<ggrid, dim3(256), 0, stream>>>(x, Wk, k, M_ROWS, C_DIM, C_DIM, rope, nullptr);
    gemm_k<<<ggrid, dim3(256), 0, stream>>>(x, Wv, v, M_ROWS, C_DIM, C_DIM, nullptr, nullptr);
    // 4) scan
    scan_k<<<dim3(16, H_N, B_DIM), dim3(256), 0, stream>>>(q, k, v, beta, mix, mask, y);
    // 5) output projection + bias
    gemm_k<<<ggrid, dim3(256), 0, stream>>>(y, Wo, out, M_ROWS, C_DIM, C_DIM, nullptr, bo);
}

// Round 3
// 599.018 us; speedup vs baseline: 1.5545x; 1.2049x over previous
//
#include <hip/hip_runtime.h>

typedef __attribute__((ext_vector_type(4))) float f32x4;
typedef __attribute__((ext_vector_type(8))) __bf16 bf16x8;

#define T_DIM 2048
#define B_DIM 4
#define C_DIM 1024
#define H_N 8
#define D_H 128
#define M_ROWS 8192   // B*T
#define MC ((size_t)M_ROWS * C_DIM)

// ---------------- RoPE cos/sin table: [T][64] float2 ----------------
__global__ void rope_table_k(float2* __restrict__ tab) {
    int idx = blockIdx.x * 256 + threadIdx.x;
    if (idx >= T_DIM * 64) return;
    int t = idx >> 6, i = idx & 63;
    float freq = expf(-(2.0f * (float)i / 128.0f) * 9.210340371976184f);
    float a = (float)t * freq;
    tab[idx] = make_float2(cosf(a), sinf(a));
}

// ---------------- beta / mix heads ----------------
__global__ __launch_bounds__(256) void betamix_k(
    const float* __restrict__ x,
    const float* __restrict__ Wb, const float* __restrict__ bb,
    const float* __restrict__ Wm, const float* __restrict__ bm,
    float* __restrict__ beta, float* __restrict__ mix) {
    int row = blockIdx.x * 8 + (threadIdx.x >> 5);
    int c = threadIdx.x & 31;
    bool is_mix = c >= 16;
    int col = c & 15;
    const float* W = is_mix ? Wm : Wb;
    const float* xr = x + (size_t)row * C_DIM;
    float acc = 0.f;
    for (int k = 0; k < C_DIM; k += 4) {
        f32x4 xv = *(const f32x4*)(xr + k);
        acc += xv.x * W[(k + 0) * 16 + col];
        acc += xv.y * W[(k + 1) * 16 + col];
        acc += xv.z * W[(k + 2) * 16 + col];
        acc += xv.w * W[(k + 3) * 16 + col];
    }
    acc += is_mix ? bm[col] : bb[col];
    if (!is_mix) {
        beta[(size_t)row * 16 + col] = 1.f / (1.f + expf(-acc));
    } else {
        float other = __shfl_xor(acc, 1);
        float mx = fmaxf(acc, other);
        float e = expf(acc - mx), eo = expf(other - mx);
        mix[(size_t)row * 16 + col] = e / (e + eo);
    }
}

// ---------------- bf16 MFMA GEMM ----------------
// AMODE 0: A fp32; AMODE 1: A = bf16 pair (Ap + A2p summed at stage).
// OUTBF: store bf16 instead of f32.
#define BKG 32
template<int AMODE, bool OUTBF>
__global__ __launch_bounds__(256) void gemm_k(
    const void* __restrict__ Ap, const void* __restrict__ A2p,
    const float* __restrict__ Bm, void* __restrict__ Cp,
    int M, int N, int K,
    const float2* __restrict__ rope_tab, const float* __restrict__ bias) {
    __shared__ __bf16 As[128][BKG + 8];
    __shared__ __bf16 Bs[128][BKG + 8];

    int tid = threadIdx.x;
    int nTilesN = N / 128;
    int bm_i = blockIdx.x / nTilesN, bn_i = blockIdx.x % nTilesN;
    int m_base = bm_i * 128, n_base = bn_i * 128;
    int wave = tid >> 6, lane = tid & 63;
    int wm = (wave >> 1) * 64, wn = (wave & 1) * 64;
    int lrow = lane & 15, lgrp = lane >> 4;

    f32x4 acc[4][4] = {};

    for (int k0 = 0; k0 < K; k0 += BKG) {
        __syncthreads();
        if (AMODE == 0) {
            const float* A = (const float*)Ap;
            #pragma unroll
            for (int it = 0; it < 4; ++it) {
                int f = tid + it * 256;
                int r = f >> 3, c4 = (f & 7) * 4;
                f32x4 v = *(const f32x4*)(A + (size_t)(m_base + r) * K + k0 + c4);
                __bf16* d = &As[r][c4];
                d[0] = (__bf16)v.x; d[1] = (__bf16)v.y; d[2] = (__bf16)v.z; d[3] = (__bf16)v.w;
            }
        } else {
            const __bf16* A = (const __bf16*)Ap;
            const __bf16* A2 = (const __bf16*)A2p;
            #pragma unroll
            for (int it = 0; it < 2; ++it) {
                int f = tid + it * 256;
                int r = f >> 2, c8 = (f & 3) * 8;
                size_t g = (size_t)(m_base + r) * K + k0 + c8;
                bf16x8 u = *(const bf16x8*)(A + g);
                bf16x8 u2 = *(const bf16x8*)(A2 + g);
                bf16x8 o;
                #pragma unroll
                for (int j = 0; j < 8; ++j)
                    o[j] = (__bf16)((float)u[j] + (float)u2[j]);
                *(bf16x8*)&As[r][c8] = o;
            }
        }
        #pragma unroll
        for (int it = 0; it < 4; ++it) {
            int f = tid + it * 256;
            int kr = f & 31, n4 = (f >> 5) * 4;
            f32x4 v = *(const f32x4*)(Bm + (size_t)(k0 + kr) * N + n_base + n4);
            Bs[n4 + 0][kr] = (__bf16)v.x;
            Bs[n4 + 1][kr] = (__bf16)v.y;
            Bs[n4 + 2][kr] = (__bf16)v.z;
            Bs[n4 + 3][kr] = (__bf16)v.w;
        }
        __syncthreads();

        bf16x8 af[4], bf[4];
        #pragma unroll
        for (int i = 0; i < 4; ++i) {
            af[i] = *(const bf16x8*)&As[wm + i * 16 + lrow][lgrp * 8];
            bf[i] = *(const bf16x8*)&Bs[wn + i * 16 + lrow][lgrp * 8];
        }
        #pragma unroll
        for (int i = 0; i < 4; ++i)
            #pragma unroll
            for (int j = 0; j < 4; ++j)
                acc[i][j] = __builtin_amdgcn_mfma_f32_16x16x32_bf16(af[i], bf[j], acc[i][j], 0, 0, 0);
    }

    bool do_rope = rope_tab != nullptr;
    #pragma unroll
    for (int i = 0; i < 4; ++i) {
        #pragma unroll
        for (int j = 0; j < 4; ++j) {
            #pragma unroll
            for (int r = 0; r < 4; ++r) {
                int grow = m_base + wm + i * 16 + (lgrp << 2) + r;
                int gcol = n_base + wn + j * 16 + lrow;
                float val = acc[i][j][r];
                if (do_rope) {
                    float partner = __shfl_xor(val, 1);
                    int t = grow & (T_DIM - 1);
                    int ii = (gcol & 127) >> 1;
                    float2 cs = rope_tab[t * 64 + ii];
                    val = (gcol & 1) ? (partner * cs.y + val * cs.x)
                                     : (val * cs.x - partner * cs.y);
                }
                if (bias) val += bias[gcol];
                size_t idx = (size_t)grow * N + gcol;
                if (OUTBF) ((__bf16*)Cp)[idx] = (__bf16)val;
                else       ((float*)Cp)[idx] = val;
            }
        }
    }
}

// ---------------- chunked MFMA scan --------------------------------
// grid (4 e-chunks of 32, K=2, B*H=32) = 256 blocks x 128 threads (2 waves).
// Wave w owns S[128 d][16 e] fp32 in 8 f32x4 accumulators.
// Per chunk L=32:  cum = inclusive prefix prod of beta (masked->1)
//   Q'' = mix*cum*q ; K' = cumL*rcum[s]*k ; V masked
//   P_w[t,s] = rcum[s]*(Q''K^T)[t,s]  (causal s<=t)
//   y = P_w @ V + Q'' @ S_prev ;  S = cumL*S + K'^T @ V
__global__ __launch_bounds__(128) void scan_k(
    const __bf16* __restrict__ qg, const __bf16* __restrict__ kg,
    const __bf16* __restrict__ vg,
    const float* __restrict__ beta, const float* __restrict__ mixp,
    const int* __restrict__ mask, __bf16* __restrict__ ybase) {

    __shared__ __bf16 Qs[32][136];      // Q'' rows t (padded)
    __shared__ __bf16 Ks[32][136];      // plain K rows s
    __shared__ __bf16 KTs[128][40];     // K'^T rows d
    __shared__ __bf16 VTs[32][40];      // V^T rows e_local
    __shared__ __bf16 Ps[32][40];       // P_w rows t
    __shared__ __bf16 STs[2][16][136];  // per-wave S^T rows e_local
    __shared__ float cumf[32], rcumf[32], wvf[32], qscf[32], mkf[32];
    __shared__ float cumLs;

    int tid = threadIdx.x;
    int w = tid >> 6, l = tid & 63;
    int lr = l & 15, lg = l >> 4;
    int e0 = blockIdx.x * 32;
    int kk = blockIdx.y;
    int b = blockIdx.z >> 3, h = blockIdx.z & 7;
    size_t rowb = (size_t)b * T_DIM;
    __bf16* yg = ybase + (size_t)kk * MC;

    f32x4 S[8] = {};

    for (int t0 = 0; t0 < T_DIM; t0 += 32) {
        __syncthreads();
        // phase 1: decay weights + prefix products (lanes 0..31 of wave 0)
        if (tid < 32) {
            int s = tid;
            size_t row = rowb + t0 + s;
            int mk = mask[row];
            float mf = mk ? 1.f : 0.f;
            size_t r16 = row * 16 + (size_t)h * 2 + kk;
            float bt = mk ? beta[r16] : 1.f;
            float mx = mixp[r16] * mf;
            float cum = bt;
            #pragma unroll
            for (int off = 1; off < 32; off <<= 1) {
                float p = __shfl(cum, (s >= off) ? (s - off) : 0);
                if (s >= off) cum *= p;
            }
            float rc = 1.f / cum;
            float cl = __shfl(cum, 31);
            cumf[s] = cum; rcumf[s] = rc; wvf[s] = cl * rc;
            qscf[s] = cum * mx; mkf[s] = mf;
            if (s == 0) cumLs = cl;
        }
        __syncthreads();

        // phase 2: stage Q'', K, K'^T, V^T
        #pragma unroll
        for (int it = 0; it < 4; ++it) {
            int f = tid + it * 128;          // 512 chunks of 8 bf16
            int s = f >> 4, c8 = (f & 15) * 8;
            size_t g = (rowb + t0 + s) * C_DIM + h * D_H + c8;
            bf16x8 qv = *(const bf16x8*)(qg + g);
            bf16x8 kv = *(const bf16x8*)(kg + g);
            float qs = qscf[s], ws = wvf[s];
            bf16x8 qo;
            #pragma unroll
            for (int j = 0; j < 8; ++j) {
                qo[j] = (__bf16)(qs * (float)qv[j]);
                KTs[c8 + j][s] = (__bf16)(ws * (float)kv[j]);
            }
            *(bf16x8*)&Qs[s][c8] = qo;
            *(bf16x8*)&Ks[s][c8] = kv;
        }
        {
            int s = tid >> 2, c8 = (tid & 3) * 8;
            size_t g = (rowb + t0 + s) * C_DIM + h * D_H + e0 + c8;
            bf16x8 vv = *(const bf16x8*)(vg + g);
            float mf = mkf[s];
            #pragma unroll
            for (int j = 0; j < 8; ++j)
                VTs[c8 + j][s] = (__bf16)(mf * (float)vv[j]);
        }
        __syncthreads();

        // phase 3: P = Q''K^T ; scale+causal -> Ps ; stage S^T (old S)
        f32x4 P[2][2] = {};
        bf16x8 aQ[2][4];
        #pragma unroll
        for (int mt = 0; mt < 2; ++mt)
            #pragma unroll
            for (int kt = 0; kt < 4; ++kt)
                aQ[mt][kt] = *(const bf16x8*)&Qs[mt * 16 + lr][kt * 32 + lg * 8];
        #pragma unroll
        for (int nt = 0; nt < 2; ++nt) {
            #pragma unroll
            for (int kt = 0; kt < 4; ++kt) {
                bf16x8 bk = *(const bf16x8*)&Ks[nt * 16 + lr][kt * 32 + lg * 8];
                P[0][nt] = __builtin_amdgcn_mfma_f32_16x16x32_bf16(aQ[0][kt], bk, P[0][nt], 0, 0, 0);
                P[1][nt] = __builtin_amdgcn_mfma_f32_16x16x32_bf16(aQ[1][kt], bk, P[1][nt], 0, 0, 0);
            }
        }
        {
            int mt = w;   // wave w writes rows 16w..16w+15
            #pragma unroll
            for (int nt = 0; nt < 2; ++nt) {
                int scol = nt * 16 + lr;
                float rc = rcumf[scol];
                #pragma unroll
                for (int r = 0; r < 4; ++r) {
                    int trow = mt * 16 + lg * 4 + r;
                    float pv = (scol <= trow) ? P[mt][nt][r] * rc : 0.f;
                    Ps[trow][scol] = (__bf16)pv;
                }
            }
        }
        #pragma unroll
        for (int dt = 0; dt < 8; ++dt) {
            int d0 = dt * 16 + lg * 4;
            STs[w][lr][d0 + 0] = (__bf16)S[dt][0];
            STs[w][lr][d0 + 1] = (__bf16)S[dt][1];
            STs[w][lr][d0 + 2] = (__bf16)S[dt][2];
            STs[w][lr][d0 + 3] = (__bf16)S[dt][3];
        }
        __syncthreads();

        // phase 4: y = PV + Q''S ; S = cumL*S + K'^T V ; store y
        f32x4 yA[2] = {};
        bf16x8 bV = *(const bf16x8*)&VTs[w * 16 + lr][lg * 8];
        #pragma unroll
        for (int mt = 0; mt < 2; ++mt) {
            bf16x8 aP = *(const bf16x8*)&Ps[mt * 16 + lr][lg * 8];
            yA[mt] = __builtin_amdgcn_mfma_f32_16x16x32_bf16(aP, bV, yA[mt], 0, 0, 0);
        }
        #pragma unroll
        for (int kt = 0; kt < 4; ++kt) {
            bf16x8 bS = *(const bf16x8*)&STs[w][lr][kt * 32 + lg * 8];
            yA[0] = __builtin_amdgcn_mfma_f32_16x16x32_bf16(aQ[0][kt], bS, yA[0], 0, 0, 0);
            yA[1] = __builtin_amdgcn_mfma_f32_16x16x32_bf16(aQ[1][kt], bS, yA[1], 0, 0, 0);
        }
        float cl = cumLs;
        #pragma unroll
        for (int dt = 0; dt < 8; ++dt) {
            bf16x8 aK = *(const bf16x8*)&KTs[dt * 16 + lr][lg * 8];
            S[dt] = S[dt] * cl;
            S[dt] = __builtin_amdgcn_mfma_f32_16x16x32_bf16(aK, bV, S[dt], 0, 0, 0);
        }
        #pragma unroll
        for (int mt = 0; mt < 2; ++mt) {
            #pragma unroll
            for (int r = 0; r < 4; ++r) {
                int trow = t0 + mt * 16 + lg * 4 + r;
                int col = h * D_H + e0 + w * 16 + lr;
                yg[(rowb + trow) * C_DIM + col] = (__bf16)yA[mt][r];
            }
        }
    }
}

extern "C" void kernel_launch(void* const* d_in, const int* in_sizes, int n_in,
                              void* d_out, int out_size, void* d_ws, size_t ws_size,
                              hipStream_t stream) {
    const float* x    = (const float*)d_in[0];
    const int*   mask = (const int*)d_in[1];
    const float* Wq   = (const float*)d_in[2];
    const float* Wk   = (const float*)d_in[3];
    const float* Wv   = (const float*)d_in[4];
    const float* Wb   = (const float*)d_in[5];
    const float* bb   = (const float*)d_in[6];
    const float* Wm   = (const float*)d_in[7];
    const float* bm   = (const float*)d_in[8];
    const float* Wo   = (const float*)d_in[9];
    const float* bo   = (const float*)d_in[10];
    float* out = (float*)d_out;

    __bf16* q  = (__bf16*)d_ws;
    __bf16* k  = q + MC;
    __bf16* v  = k + MC;
    __bf16* y0 = v + MC;               // y0 and y1 back-to-back (2*MC)
    float* beta = (float*)(y0 + 2 * MC);
    float* mixb = beta + M_ROWS * 16;
    float2* rope = (float2*)(mixb + M_ROWS * 16);

    rope_table_k<<<dim3((T_DIM * 64) / 256), dim3(256), 0, stream>>>(rope);
    betamix_k<<<dim3(M_ROWS / 8), dim3(256), 0, stream>>>(x, Wb, bb, Wm, bm, beta, mixb);

    dim3 ggrid((M_ROWS / 128) * (C_DIM / 128));
    gemm_k<0, true><<<ggrid, dim3(256), 0, stream>>>(x, nullptr, Wq, q, M_ROWS, C_DIM, C_DIM, rope, nullptr);
    gemm_k<0, true><<<ggrid, dim3(256), 0, stream>>>(x, nullptr, Wk, k, M_ROWS, C_DIM, C_DIM, rope, nullptr);
    gemm_k<0, true><<<ggrid, dim3(256), 0, stream>>>(x, nullptr, Wv, v, M_ROWS, C_DIM, C_DIM, nullptr, nullptr);

    scan_k<<<dim3(4, 2, 32), dim3(128), 0, stream>>>(q, k, v, beta, mixb, mask, y0);

    gemm_k<1, false><<<ggrid, dim3(256), 0, stream>>>(y0, y0 + MC, Wo, out, M_ROWS, C_DIM, C_DIM, nullptr, bo);
}

// Round 4
// 416.111 us; speedup vs baseline: 2.2378x; 1.4396x over previous
//
#include <hip/hip_runtime.h>

typedef __attribute__((ext_vector_type(4))) float f32x4;
typedef __attribute__((ext_vector_type(8))) __bf16 bf16x8;

#define T_DIM 2048
#define B_DIM 4
#define C_DIM 1024
#define H_N 8
#define D_H 128
#define M_ROWS 8192   // B*T
#define MC ((size_t)M_ROWS * C_DIM)
#define LCH 64               // chunk length
#define NCH (T_DIM / LCH)    // 32 chunks
#define CHSZ (128 * 128)     // state tile elements
// XOR swizzle (element col, 8-wide blocks) for transposed [r][64] bf16 tiles
#define SWE(r) ((((r) ^ ((r) >> 3)) & 7) << 3)

// ---------------- RoPE cos/sin table: [T][64] float2 ----------------
__global__ void rope_table_k(float2* __restrict__ tab) {
    int idx = blockIdx.x * 256 + threadIdx.x;
    if (idx >= T_DIM * 64) return;
    int t = idx >> 6, i = idx & 63;
    float freq = expf(-(2.0f * (float)i / 128.0f) * 9.210340371976184f);
    float a = (float)t * freq;
    tab[idx] = make_float2(cosf(a), sinf(a));
}

// ---------------- beta / mix heads ----------------
__global__ __launch_bounds__(256) void betamix_k(
    const float* __restrict__ x,
    const float* __restrict__ Wb, const float* __restrict__ bb,
    const float* __restrict__ Wm, const float* __restrict__ bm,
    float* __restrict__ beta, float* __restrict__ mix) {
    int row = blockIdx.x * 8 + (threadIdx.x >> 5);
    int c = threadIdx.x & 31;
    bool is_mix = c >= 16;
    int col = c & 15;
    const float* W = is_mix ? Wm : Wb;
    const float* xr = x + (size_t)row * C_DIM;
    float acc = 0.f;
    for (int k = 0; k < C_DIM; k += 4) {
        f32x4 xv = *(const f32x4*)(xr + k);
        acc += xv.x * W[(k + 0) * 16 + col];
        acc += xv.y * W[(k + 1) * 16 + col];
        acc += xv.z * W[(k + 2) * 16 + col];
        acc += xv.w * W[(k + 3) * 16 + col];
    }
    acc += is_mix ? bm[col] : bb[col];
    if (!is_mix) {
        beta[(size_t)row * 16 + col] = 1.f / (1.f + expf(-acc));
    } else {
        float other = __shfl_xor(acc, 1);
        float mx = fmaxf(acc, other);
        float e = expf(acc - mx), eo = expf(other - mx);
        mix[(size_t)row * 16 + col] = e / (e + eo);
    }
}

// ---------------- bf16 MFMA GEMM ----------------
#define BKG 32
template<int AMODE, bool OUTBF>
__global__ __launch_bounds__(256) void gemm_k(
    const void* __restrict__ Ap, const void* __restrict__ A2p,
    const float* __restrict__ Bm, void* __restrict__ Cp,
    int M, int N, int K,
    const float2* __restrict__ rope_tab, const float* __restrict__ bias) {
    __shared__ __bf16 As[128][BKG + 8];
    __shared__ __bf16 Bs[128][BKG + 8];

    int tid = threadIdx.x;
    int nTilesN = N / 128;
    int bm_i = blockIdx.x / nTilesN, bn_i = blockIdx.x % nTilesN;
    int m_base = bm_i * 128, n_base = bn_i * 128;
    int wave = tid >> 6, lane = tid & 63;
    int wm = (wave >> 1) * 64, wn = (wave & 1) * 64;
    int lrow = lane & 15, lgrp = lane >> 4;

    f32x4 acc[4][4] = {};

    for (int k0 = 0; k0 < K; k0 += BKG) {
        __syncthreads();
        if (AMODE == 0) {
            const float* A = (const float*)Ap;
            #pragma unroll
            for (int it = 0; it < 4; ++it) {
                int f = tid + it * 256;
                int r = f >> 3, c4 = (f & 7) * 4;
                f32x4 v = *(const f32x4*)(A + (size_t)(m_base + r) * K + k0 + c4);
                __bf16* d = &As[r][c4];
                d[0] = (__bf16)v.x; d[1] = (__bf16)v.y; d[2] = (__bf16)v.z; d[3] = (__bf16)v.w;
            }
        } else {
            const __bf16* A = (const __bf16*)Ap;
            const __bf16* A2 = (const __bf16*)A2p;
            #pragma unroll
            for (int it = 0; it < 2; ++it) {
                int f = tid + it * 256;
                int r = f >> 2, c8 = (f & 3) * 8;
                size_t g = (size_t)(m_base + r) * K + k0 + c8;
                bf16x8 u = *(const bf16x8*)(A + g);
                bf16x8 u2 = *(const bf16x8*)(A2 + g);
                bf16x8 o;
                #pragma unroll
                for (int j = 0; j < 8; ++j)
                    o[j] = (__bf16)((float)u[j] + (float)u2[j]);
                *(bf16x8*)&As[r][c8] = o;
            }
        }
        #pragma unroll
        for (int it = 0; it < 4; ++it) {
            int f = tid + it * 256;
            int kr = f & 31, n4 = (f >> 5) * 4;
            f32x4 v = *(const f32x4*)(Bm + (size_t)(k0 + kr) * N + n_base + n4);
            Bs[n4 + 0][kr] = (__bf16)v.x;
            Bs[n4 + 1][kr] = (__bf16)v.y;
            Bs[n4 + 2][kr] = (__bf16)v.z;
            Bs[n4 + 3][kr] = (__bf16)v.w;
        }
        __syncthreads();

        bf16x8 af[4], bf[4];
        #pragma unroll
        for (int i = 0; i < 4; ++i) {
            af[i] = *(const bf16x8*)&As[wm + i * 16 + lrow][lgrp * 8];
            bf[i] = *(const bf16x8*)&Bs[wn + i * 16 + lrow][lgrp * 8];
        }
        #pragma unroll
        for (int i = 0; i < 4; ++i)
            #pragma unroll
            for (int j = 0; j < 4; ++j)
                acc[i][j] = __builtin_amdgcn_mfma_f32_16x16x32_bf16(af[i], bf[j], acc[i][j], 0, 0, 0);
    }

    bool do_rope = rope_tab != nullptr;
    #pragma unroll
    for (int i = 0; i < 4; ++i) {
        #pragma unroll
        for (int j = 0; j < 4; ++j) {
            #pragma unroll
            for (int r = 0; r < 4; ++r) {
                int grow = m_base + wm + i * 16 + (lgrp << 2) + r;
                int gcol = n_base + wn + j * 16 + lrow;
                float val = acc[i][j][r];
                if (do_rope) {
                    float partner = __shfl_xor(val, 1);
                    int t = grow & (T_DIM - 1);
                    int ii = (gcol & 127) >> 1;
                    float2 cs = rope_tab[t * 64 + ii];
                    val = (gcol & 1) ? (partner * cs.y + val * cs.x)
                                     : (val * cs.x - partner * cs.y);
                }
                if (bias) val += bias[gcol];
                size_t idx = (size_t)grow * N + gcol;
                if (OUTBF) ((__bf16*)Cp)[idx] = (__bf16)val;
                else       ((float*)Cp)[idx] = val;
            }
        }
    }
}

// ============ chunk-parallel scan: 3 passes ============
// Pass A: per-chunk summary  B^T_c[e][d] = sum_s (mf*v)[s][e] * (wv*k)[s][d],
//         wv_s = cumL/cum_s ; also cumL_c. grid (NCH, K, BH) = 2048 blocks.
__global__ __launch_bounds__(256) void chunk_sum_k(
    const __bf16* __restrict__ kg, const __bf16* __restrict__ vg,
    const float* __restrict__ beta, const int* __restrict__ mask,
    __bf16* __restrict__ BT, float* __restrict__ cumLg) {
    __shared__ __bf16 KT[128 * 64];
    __shared__ __bf16 VT[128 * 64];
    __shared__ float wvf[LCH], mkf[LCH];

    int tid = threadIdx.x;
    int c = blockIdx.x, kk = blockIdx.y, bh = blockIdx.z;
    int b = bh >> 3, h = bh & 7;
    int scan = bh * 2 + kk;
    size_t rowb = (size_t)b * T_DIM + c * LCH;

    if (tid < 64) {
        int s = tid;
        size_t row = rowb + s;
        int mk = mask[row];
        float mf = mk ? 1.f : 0.f;
        float bt = mk ? beta[row * 16 + h * 2 + kk] : 1.f;
        float cum = bt;
        #pragma unroll
        for (int off = 1; off < 64; off <<= 1) {
            float p = __shfl(cum, (s >= off) ? s - off : 0);
            if (s >= off) cum *= p;
        }
        float cl = __shfl(cum, 63);
        wvf[s] = cl / cum;
        mkf[s] = mf;
        if (s == 63) cumLg[scan * NCH + c] = cum;
    }
    __syncthreads();

    // stage K'^T[d][s], V^T[e][s] (swizzled)
    #pragma unroll
    for (int it = 0; it < 4; ++it) {
        int f = tid + it * 256;
        int s = f >> 4, c8 = (f & 15) * 8;
        size_t g = (rowb + s) * C_DIM + h * D_H + c8;
        bf16x8 kv = *(const bf16x8*)(kg + g);
        bf16x8 vv = *(const bf16x8*)(vg + g);
        float ws_ = wvf[s], mf = mkf[s];
        #pragma unroll
        for (int j = 0; j < 8; ++j) {
            int d = c8 + j;
            KT[d * 64 + (s ^ SWE(d))] = (__bf16)(ws_ * (float)kv[j]);
            VT[d * 64 + (s ^ SWE(d))] = (__bf16)(mf * (float)vv[j]);
        }
    }
    __syncthreads();

    int w = tid >> 6, l = tid & 63;
    int lr = l & 15, lg = l >> 4;
    f32x4 acc[2][8] = {};
    #pragma unroll
    for (int kt = 0; kt < 2; ++kt) {
        int col = kt * 32 + lg * 8;
        bf16x8 aV[2], bK[8];
        #pragma unroll
        for (int et = 0; et < 2; ++et) {
            int e = w * 32 + et * 16 + lr;
            aV[et] = *(const bf16x8*)&VT[e * 64 + (col ^ SWE(e))];
        }
        #pragma unroll
        for (int dt = 0; dt < 8; ++dt) {
            int d = dt * 16 + lr;
            bK[dt] = *(const bf16x8*)&KT[d * 64 + (col ^ SWE(d))];
        }
        #pragma unroll
        for (int et = 0; et < 2; ++et)
            #pragma unroll
            for (int dt = 0; dt < 8; ++dt)
                acc[et][dt] = __builtin_amdgcn_mfma_f32_16x16x32_bf16(aV[et], bK[dt], acc[et][dt], 0, 0, 0);
    }

    __bf16* bout = BT + ((size_t)scan * NCH + c) * CHSZ;
    #pragma unroll
    for (int et = 0; et < 2; ++et)
        #pragma unroll
        for (int dt = 0; dt < 8; ++dt)
            #pragma unroll
            for (int r = 0; r < 4; ++r) {
                int e = w * 32 + et * 16 + lg * 4 + r;
                bout[e * 128 + dt * 16 + lr] = (__bf16)acc[et][dt][r];
            }
}

// Pass B: in-place inter-chunk recurrence. BT[c] := S_start(c);
//         S = cumL_c * S + B_c.  512 blocks x 256 threads, 8 el/thread.
__global__ __launch_bounds__(256) void chunk_scan_k(
    __bf16* __restrict__ BT, const float* __restrict__ cumLg) {
    int bid = blockIdx.x;
    int scan = bid >> 3, part = bid & 7;
    int tid = threadIdx.x;
    int e = part * 16 + (tid >> 4);
    int d0 = (tid & 15) * 8;
    __bf16* base = BT + (size_t)scan * NCH * CHSZ + e * 128 + d0;
    const float* cl = cumLg + scan * NCH;
    float acc[8] = {};
    for (int c = 0; c < NCH; ++c) {
        bf16x8 bv = *(const bf16x8*)(base + (size_t)c * CHSZ);
        float g = cl[c];
        bf16x8 so;
        #pragma unroll
        for (int j = 0; j < 8; ++j) so[j] = (__bf16)acc[j];
        *(bf16x8*)(base + (size_t)c * CHSZ) = so;
        #pragma unroll
        for (int j = 0; j < 8; ++j) acc[j] = g * acc[j] + (float)bv[j];
    }
}

// Pass C: per-chunk output y = P_w @ V + Q'' @ S_start.
//         grid (NCH, K, BH) = 2048 blocks x 4 waves; wave w owns t-rows 16w..16w+15.
__global__ __launch_bounds__(256) void chunk_out_k(
    const __bf16* __restrict__ qg, const __bf16* __restrict__ kg,
    const __bf16* __restrict__ vg, const __bf16* __restrict__ ST,
    const float* __restrict__ beta, const float* __restrict__ mixp,
    const int* __restrict__ mask, __bf16* __restrict__ ybase) {
    __shared__ __bf16 Qs[64 * 136];
    __shared__ __bf16 Ks[64 * 136];
    __shared__ __bf16 VT[128 * 64];
    __shared__ __bf16 Ps[64 * 72];
    __shared__ float rcumf[LCH], qscf[LCH], mkf[LCH];

    int tid = threadIdx.x;
    int c = blockIdx.x, kk = blockIdx.y, bh = blockIdx.z;
    int b = bh >> 3, h = bh & 7;
    size_t rowb = (size_t)b * T_DIM + c * LCH;
    __bf16* yg = ybase + (size_t)kk * MC;

    if (tid < 64) {
        int s = tid;
        size_t row = rowb + s;
        int mk = mask[row];
        float mf = mk ? 1.f : 0.f;
        float bt = mk ? beta[row * 16 + h * 2 + kk] : 1.f;
        float cum = bt;
        #pragma unroll
        for (int off = 1; off < 64; off <<= 1) {
            float p = __shfl(cum, (s >= off) ? s - off : 0);
            if (s >= off) cum *= p;
        }
        rcumf[s] = 1.f / cum;
        qscf[s] = cum * (mk ? mixp[row * 16 + h * 2 + kk] : 0.f);
        mkf[s] = mf;
    }
    __syncthreads();

    // stage Q''(scaled) and K rows, V^T (swizzled)
    #pragma unroll
    for (int it = 0; it < 4; ++it) {
        int f = tid + it * 256;
        int t = f >> 4, c8 = (f & 15) * 8;
        size_t g = (rowb + t) * C_DIM + h * D_H + c8;
        bf16x8 qv = *(const bf16x8*)(qg + g);
        bf16x8 kv = *(const bf16x8*)(kg + g);
        float qs = qscf[t];
        bf16x8 qo;
        #pragma unroll
        for (int j = 0; j < 8; ++j) qo[j] = (__bf16)(qs * (float)qv[j]);
        *(bf16x8*)&Qs[t * 136 + c8] = qo;
        *(bf16x8*)&Ks[t * 136 + c8] = kv;
    }
    #pragma unroll
    for (int it = 0; it < 4; ++it) {
        int f = tid + it * 256;
        int s = f >> 4, c8 = (f & 15) * 8;
        size_t g = (rowb + s) * C_DIM + h * D_H + c8;
        bf16x8 vv = *(const bf16x8*)(vg + g);
        float mf = mkf[s];
        #pragma unroll
        for (int j = 0; j < 8; ++j) {
            int e = c8 + j;
            VT[e * 64 + (s ^ SWE(e))] = (__bf16)(mf * (float)vv[j]);
        }
    }
    __syncthreads();

    int w = tid >> 6, l = tid & 63;
    int lr = l & 15, lg = l >> 4;

    bf16x8 aQ[4];
    #pragma unroll
    for (int kt = 0; kt < 4; ++kt)
        aQ[kt] = *(const bf16x8*)&Qs[(w * 16 + lr) * 136 + kt * 32 + lg * 8];

    // P = Q''K^T ; causal * rcum -> Ps (wave-local rows)
    #pragma unroll
    for (int st = 0; st < 4; ++st) {
        f32x4 p = {};
        #pragma unroll
        for (int kt = 0; kt < 4; ++kt) {
            bf16x8 bk = *(const bf16x8*)&Ks[(st * 16 + lr) * 136 + kt * 32 + lg * 8];
            p = __builtin_amdgcn_mfma_f32_16x16x32_bf16(aQ[kt], bk, p, 0, 0, 0);
        }
        #pragma unroll
        for (int r = 0; r < 4; ++r) {
            int tl = w * 16 + lg * 4 + r;
            int sc = st * 16 + lr;
            float pv = (sc <= tl) ? p[r] * rcumf[sc] : 0.f;
            Ps[tl * 72 + sc] = (__bf16)pv;
        }
    }

    bf16x8 aP[2];
    #pragma unroll
    for (int k2 = 0; k2 < 2; ++k2)
        aP[k2] = *(const bf16x8*)&Ps[(w * 16 + lr) * 72 + k2 * 32 + lg * 8];

    const __bf16* stb = ST + ((size_t)(bh * 2 + kk) * NCH + c) * CHSZ;
    f32x4 yA[8];
    #pragma unroll
    for (int et = 0; et < 8; ++et) {
        int e = et * 16 + lr;
        f32x4 y = {};
        #pragma unroll
        for (int k2 = 0; k2 < 2; ++k2) {
            bf16x8 bv = *(const bf16x8*)&VT[e * 64 + ((k2 * 32 + lg * 8) ^ SWE(e))];
            y = __builtin_amdgcn_mfma_f32_16x16x32_bf16(aP[k2], bv, y, 0, 0, 0);
        }
        #pragma unroll
        for (int kt = 0; kt < 4; ++kt) {
            bf16x8 bs = *(const bf16x8*)(stb + e * 128 + kt * 32 + lg * 8);
            y = __builtin_amdgcn_mfma_f32_16x16x32_bf16(aQ[kt], bs, y, 0, 0, 0);
        }
        yA[et] = y;
    }
    #pragma unroll
    for (int et = 0; et < 8; ++et)
        #pragma unroll
        for (int r = 0; r < 4; ++r) {
            size_t row = rowb + w * 16 + lg * 4 + r;
            yg[row * C_DIM + h * D_H + et * 16 + lr] = (__bf16)yA[et][r];
        }
}

extern "C" void kernel_launch(void* const* d_in, const int* in_sizes, int n_in,
                              void* d_out, int out_size, void* d_ws, size_t ws_size,
                              hipStream_t stream) {
    const float* x    = (const float*)d_in[0];
    const int*   mask = (const int*)d_in[1];
    const float* Wq   = (const float*)d_in[2];
    const float* Wk   = (const float*)d_in[3];
    const float* Wv   = (const float*)d_in[4];
    const float* Wb   = (const float*)d_in[5];
    const float* bb   = (const float*)d_in[6];
    const float* Wm   = (const float*)d_in[7];
    const float* bm   = (const float*)d_in[8];
    const float* Wo   = (const float*)d_in[9];
    const float* bo   = (const float*)d_in[10];
    float* out = (float*)d_out;

    __bf16* q  = (__bf16*)d_ws;
    __bf16* k  = q + MC;
    __bf16* v  = k + MC;
    __bf16* y0 = v + MC;                         // y0,y1: 2*MC
    __bf16* BT = y0 + 2 * MC;                    // 64 scans * 32 chunks * 16384
    float* beta = (float*)(BT + (size_t)64 * NCH * CHSZ);
    float* mixb = beta + M_ROWS * 16;
    float* cumL = mixb + M_ROWS * 16;            // 64*32
    float2* rope = (float2*)(cumL + 64 * NCH);

    rope_table_k<<<dim3((T_DIM * 64) / 256), dim3(256), 0, stream>>>(rope);
    betamix_k<<<dim3(M_ROWS / 8), dim3(256), 0, stream>>>(x, Wb, bb, Wm, bm, beta, mixb);

    dim3 ggrid((M_ROWS / 128) * (C_DIM / 128));
    gemm_k<0, true><<<ggrid, dim3(256), 0, stream>>>(x, nullptr, Wq, q, M_ROWS, C_DIM, C_DIM, rope, nullptr);
    gemm_k<0, true><<<ggrid, dim3(256), 0, stream>>>(x, nullptr, Wk, k, M_ROWS, C_DIM, C_DIM, rope, nullptr);
    gemm_k<0, true><<<ggrid, dim3(256), 0, stream>>>(x, nullptr, Wv, v, M_ROWS, C_DIM, C_DIM, nullptr, nullptr);

    chunk_sum_k<<<dim3(NCH, 2, 32), dim3(256), 0, stream>>>(k, v, beta, mask, BT, cumL);
    chunk_scan_k<<<dim3(512), dim3(256), 0, stream>>>(BT, cumL);
    chunk_out_k<<<dim3(NCH, 2, 32), dim3(256), 0, stream>>>(q, k, v, BT, beta, mixb, mask, y0);

    gemm_k<1, false><<<ggrid, dim3(256), 0, stream>>>(y0, y0 + MC, Wo, out, M_ROWS, C_DIM, C_DIM, nullptr, bo);
}

// Round 6
// 299.647 us; speedup vs baseline: 3.1076x; 1.3887x over previous
//
#include <hip/hip_runtime.h>

typedef __attribute__((ext_vector_type(4))) float f32x4;
typedef __attribute__((ext_vector_type(8))) __bf16 bf16x8;

#define T_DIM 2048
#define B_DIM 4
#define C_DIM 1024
#define H_N 8
#define D_H 128
#define M_ROWS 8192   // B*T
#define MC ((size_t)M_ROWS * C_DIM)
#define LCH 64               // chunk length
#define NCH (T_DIM / LCH)    // 32 chunks
#define CHSZ (128 * 128)     // state tile elements
// XOR swizzle (element col, 8-wide blocks) for transposed [r][64] bf16 tiles
#define SWE(r) ((((r) ^ ((r) >> 3)) & 7) << 3)

#define GLDS16(g, l) __builtin_amdgcn_global_load_lds( \
    (const __attribute__((address_space(1))) void*)(g), \
    (__attribute__((address_space(3))) void*)(l), 16, 0, 0)

// ---------------- RoPE cos/sin table ----------------
__global__ void rope_table_k(float2* __restrict__ tab) {
    int idx = blockIdx.x * 256 + threadIdx.x;
    if (idx >= T_DIM * 64) return;
    int t = idx >> 6, i = idx & 63;
    float freq = expf(-(2.0f * (float)i / 128.0f) * 9.210340371976184f);
    float a = (float)t * freq;
    tab[idx] = make_float2(cosf(a), sinf(a));
}

// ---------------- x -> bf16 ----------------
__global__ __launch_bounds__(256) void cvt_x_k(const float* __restrict__ in,
                                               __bf16* __restrict__ out) {
    int i = blockIdx.x * 256 + threadIdx.x;   // one 8-elem chunk each
    f32x4 a = ((const f32x4*)in)[i * 2];
    f32x4 b = ((const f32x4*)in)[i * 2 + 1];
    bf16x8 o;
    o[0] = (__bf16)a.x; o[1] = (__bf16)a.y; o[2] = (__bf16)a.z; o[3] = (__bf16)a.w;
    o[4] = (__bf16)b.x; o[5] = (__bf16)b.y; o[6] = (__bf16)b.z; o[7] = (__bf16)b.w;
    ((bf16x8*)out)[i] = o;
}

// ---------------- weight transpose+convert: W[K][N] f32 -> WT[N][K] bf16 ----
// 64x64 tile: load = 1024 f32x4-quads?? no: 1024 floats/4 = 256*4... load loop
// covers 64 rows x 64 cols via 4 iters of 256 (4 floats each). Store covers
// 64 n x 8 k-granules = 512 items -> 2 iters of 256.  (Round-5 bug: 4 iters.)
__global__ __launch_bounds__(256) void wtrans_k(
    const float* __restrict__ W0, const float* __restrict__ W1,
    const float* __restrict__ W2, const float* __restrict__ W3,
    __bf16* __restrict__ out) {
    const float* W = blockIdx.z == 0 ? W0 : blockIdx.z == 1 ? W1 :
                     blockIdx.z == 2 ? W2 : W3;
    __bf16* o = out + (size_t)blockIdx.z * C_DIM * C_DIM;
    __shared__ float t[64][65];
    int tid = threadIdx.x;
    int r0 = blockIdx.y * 64, c0 = blockIdx.x * 64;
    #pragma unroll
    for (int it = 0; it < 4; ++it) {
        int idx = it * 256 + tid;
        int r = idx >> 4, c4 = (idx & 15) * 4;
        f32x4 v = *(const f32x4*)(W + (size_t)(r0 + r) * C_DIM + c0 + c4);
        t[r][c4] = v.x; t[r][c4 + 1] = v.y; t[r][c4 + 2] = v.z; t[r][c4 + 3] = v.w;
    }
    __syncthreads();
    #pragma unroll
    for (int it = 0; it < 2; ++it) {
        int idx = it * 256 + tid;
        int n = idx >> 3, k8 = (idx & 7) * 8;
        bf16x8 ov;
        #pragma unroll
        for (int j = 0; j < 8; ++j) ov[j] = (__bf16)t[k8 + j][n];
        *(bf16x8*)(o + (size_t)(c0 + n) * C_DIM + r0 + k8) = ov;
    }
}

// ---------------- beta / mix heads ----------------
__global__ __launch_bounds__(256) void betamix_k(
    const float* __restrict__ x,
    const float* __restrict__ Wb, const float* __restrict__ bb,
    const float* __restrict__ Wm, const float* __restrict__ bm,
    float* __restrict__ beta, float* __restrict__ mix) {
    int row = blockIdx.x * 8 + (threadIdx.x >> 5);
    int c = threadIdx.x & 31;
    bool is_mix = c >= 16;
    int col = c & 15;
    const float* W = is_mix ? Wm : Wb;
    const float* xr = x + (size_t)row * C_DIM;
    float acc = 0.f;
    for (int k = 0; k < C_DIM; k += 4) {
        f32x4 xv = *(const f32x4*)(xr + k);
        acc += xv.x * W[(k + 0) * 16 + col];
        acc += xv.y * W[(k + 1) * 16 + col];
        acc += xv.z * W[(k + 2) * 16 + col];
        acc += xv.w * W[(k + 3) * 16 + col];
    }
    acc += is_mix ? bm[col] : bb[col];
    if (!is_mix) {
        beta[(size_t)row * 16 + col] = 1.f / (1.f + expf(-acc));
    } else {
        float other = __shfl_xor(acc, 1);
        float mx = fmaxf(acc, other);
        float e = expf(acc - mx), eo = expf(other - mx);
        mix[(size_t)row * 16 + col] = e / (e + eo);
    }
}

// ---------------- bf16 GEMM, m97 structure: A[M][K] bf16, BT[N][K] bf16 ----
// 128x128 tile, BK=64, both tiles staged via global_load_lds(16B) with
// granule swizzle (g ^ row&7) pre-applied on the global source; fragment
// reads apply the same swizzle -> conflict-free ds_read_b128.
template<bool ROPE, bool OUTF32>
__global__ __launch_bounds__(256) void gemm_bt(
    const __bf16* __restrict__ A, const __bf16* __restrict__ BT,
    void* __restrict__ Cp, int M, int N, int K,
    const float2* __restrict__ rope_tab, const float* __restrict__ bias) {
    __shared__ __bf16 As[128 * 64];
    __shared__ __bf16 Bs[128 * 64];

    int tid = threadIdx.x;
    int nTN = N >> 7;
    int bm = blockIdx.x / nTN, bn = blockIdx.x % nTN;
    int m_base = bm << 7, n_base = bn << 7;
    int w = tid >> 6, lane = tid & 63;
    int lr = lane & 15, lg = lane >> 4;
    int wm = (w >> 1) * 64, wn = (w & 1) * 64;

    // per-lane pre-swizzled global offsets + wave-uniform LDS bases
    size_t aoff[4], boff[4];
    int ldso[4];
    #pragma unroll
    for (int it = 0; it < 4; ++it) {
        int gi = it * 256 + tid;
        int row = gi >> 3;
        int g = (gi & 7) ^ (row & 7);
        aoff[it] = (size_t)(m_base + row) * K + g * 8;
        boff[it] = (size_t)(n_base + row) * K + g * 8;
        ldso[it] = (it * 256 + w * 64) * 16;   // bytes, wave-uniform
    }

    f32x4 acc[4][4] = {};

    for (int k0 = 0; k0 < K; k0 += 64) {
        __syncthreads();
        #pragma unroll
        for (int it = 0; it < 4; ++it) {
            GLDS16(A + aoff[it] + k0, (char*)As + ldso[it]);
            GLDS16(BT + boff[it] + k0, (char*)Bs + ldso[it]);
        }
        __syncthreads();
        #pragma unroll
        for (int ss = 0; ss < 2; ++ss) {
            bf16x8 af[4], bfr[4];
            #pragma unroll
            for (int i = 0; i < 4; ++i) {
                int ar = wm + i * 16 + lr;
                af[i] = *(const bf16x8*)((char*)As + ar * 128 + (((ss * 4 + lg) ^ (ar & 7)) << 4));
                int br = wn + i * 16 + lr;
                bfr[i] = *(const bf16x8*)((char*)Bs + br * 128 + (((ss * 4 + lg) ^ (br & 7)) << 4));
            }
            #pragma unroll
            for (int i = 0; i < 4; ++i)
                #pragma unroll
                for (int j = 0; j < 4; ++j)
                    acc[i][j] = __builtin_amdgcn_mfma_f32_16x16x32_bf16(af[i], bfr[j], acc[i][j], 0, 0, 0);
        }
    }

    #pragma unroll
    for (int i = 0; i < 4; ++i) {
        #pragma unroll
        for (int j = 0; j < 4; ++j) {
            #pragma unroll
            for (int r = 0; r < 4; ++r) {
                int grow = m_base + wm + i * 16 + (lg << 2) + r;
                int gcol = n_base + wn + j * 16 + lr;
                float val = acc[i][j][r];
                if (ROPE) {
                    float partner = __shfl_xor(val, 1);
                    int t = grow & (T_DIM - 1);
                    int ii = (gcol & 127) >> 1;
                    float2 cs = rope_tab[t * 64 + ii];
                    val = (gcol & 1) ? (partner * cs.y + val * cs.x)
                                     : (val * cs.x - partner * cs.y);
                }
                if (bias) val += bias[gcol];
                size_t idx = (size_t)grow * N + gcol;
                if (OUTF32) ((float*)Cp)[idx] = val;
                else        ((__bf16*)Cp)[idx] = (__bf16)val;
            }
        }
    }
}

// ============ chunk-parallel scan ============
// Pass A: per-chunk summary  B^T_c[e][d] = sum_s (mf*v)[s][e] * (wv*k)[s][d]
__global__ __launch_bounds__(256) void chunk_sum_k(
    const __bf16* __restrict__ kg, const __bf16* __restrict__ vg,
    const float* __restrict__ beta, const int* __restrict__ mask,
    __bf16* __restrict__ BT, float* __restrict__ cumLg) {
    __shared__ __bf16 KT[128 * 64];
    __shared__ __bf16 VT[128 * 64];
    __shared__ float wvf[LCH], mkf[LCH];

    int tid = threadIdx.x;
    int c = blockIdx.x, kk = blockIdx.y, bh = blockIdx.z;
    int b = bh >> 3, h = bh & 7;
    int scan = bh * 2 + kk;
    size_t rowb = (size_t)b * T_DIM + c * LCH;

    if (tid < 64) {
        int s = tid;
        size_t row = rowb + s;
        int mk = mask[row];
        float mf = mk ? 1.f : 0.f;
        float bt = mk ? beta[row * 16 + h * 2 + kk] : 1.f;
        float cum = bt;
        #pragma unroll
        for (int off = 1; off < 64; off <<= 1) {
            float p = __shfl(cum, (s >= off) ? s - off : 0);
            if (s >= off) cum *= p;
        }
        float cl = __shfl(cum, 63);
        wvf[s] = cl / cum;
        mkf[s] = mf;
        if (s == 63) cumLg[scan * NCH + c] = cum;
    }
    __syncthreads();

    #pragma unroll
    for (int it = 0; it < 4; ++it) {
        int f = tid + it * 256;
        int s = f >> 4, c8 = (f & 15) * 8;
        size_t g = (rowb + s) * C_DIM + h * D_H + c8;
        bf16x8 kv = *(const bf16x8*)(kg + g);
        bf16x8 vv = *(const bf16x8*)(vg + g);
        float ws_ = wvf[s], mf = mkf[s];
        #pragma unroll
        for (int j = 0; j < 8; ++j) {
            int d = c8 + j;
            KT[d * 64 + (s ^ SWE(d))] = (__bf16)(ws_ * (float)kv[j]);
            VT[d * 64 + (s ^ SWE(d))] = (__bf16)(mf * (float)vv[j]);
        }
    }
    __syncthreads();

    int w = tid >> 6, l = tid & 63;
    int lr = l & 15, lg = l >> 4;
    f32x4 acc[2][8] = {};
    #pragma unroll
    for (int kt = 0; kt < 2; ++kt) {
        int col = kt * 32 + lg * 8;
        bf16x8 aV[2], bK[8];
        #pragma unroll
        for (int et = 0; et < 2; ++et) {
            int e = w * 32 + et * 16 + lr;
            aV[et] = *(const bf16x8*)&VT[e * 64 + (col ^ SWE(e))];
        }
        #pragma unroll
        for (int dt = 0; dt < 8; ++dt) {
            int d = dt * 16 + lr;
            bK[dt] = *(const bf16x8*)&KT[d * 64 + (col ^ SWE(d))];
        }
        #pragma unroll
        for (int et = 0; et < 2; ++et)
            #pragma unroll
            for (int dt = 0; dt < 8; ++dt)
                acc[et][dt] = __builtin_amdgcn_mfma_f32_16x16x32_bf16(aV[et], bK[dt], acc[et][dt], 0, 0, 0);
    }

    __bf16* bout = BT + ((size_t)scan * NCH + c) * CHSZ;
    #pragma unroll
    for (int et = 0; et < 2; ++et)
        #pragma unroll
        for (int dt = 0; dt < 8; ++dt)
            #pragma unroll
            for (int r = 0; r < 4; ++r) {
                int e = w * 32 + et * 16 + lg * 4 + r;
                bout[e * 128 + dt * 16 + lr] = (__bf16)acc[et][dt][r];
            }
}

// Pass B: in-place inter-chunk recurrence. BT[c] := S_start(c)
__global__ __launch_bounds__(256) void chunk_scan_k(
    __bf16* __restrict__ BT, const float* __restrict__ cumLg) {
    int bid = blockIdx.x;
    int scan = bid >> 3, part = bid & 7;
    int tid = threadIdx.x;
    int e = part * 16 + (tid >> 4);
    int d0 = (tid & 15) * 8;
    __bf16* base = BT + (size_t)scan * NCH * CHSZ + e * 128 + d0;
    const float* cl = cumLg + scan * NCH;
    float acc[8] = {};
    for (int c = 0; c < NCH; ++c) {
        bf16x8 bv = *(const bf16x8*)(base + (size_t)c * CHSZ);
        float g = cl[c];
        bf16x8 so;
        #pragma unroll
        for (int j = 0; j < 8; ++j) so[j] = (__bf16)acc[j];
        *(bf16x8*)(base + (size_t)c * CHSZ) = so;
        #pragma unroll
        for (int j = 0; j < 8; ++j) acc[j] = g * acc[j] + (float)bv[j];
    }
}

// Pass C (merged kk): Praw = qK^T once; per kk: y += (qsc*rcum*P)@V + qsc*(q@S_kk)
// grid (NCH, BH) = 1024 blocks x 4 waves; wave w owns t-rows 16w..16w+15.
__global__ __launch_bounds__(256) void chunk_out_k(
    const __bf16* __restrict__ qg, const __bf16* __restrict__ kg,
    const __bf16* __restrict__ vg, const __bf16* __restrict__ ST,
    const float* __restrict__ beta, const float* __restrict__ mixp,
    const int* __restrict__ mask, __bf16* __restrict__ yg) {
    __shared__ __bf16 Qs[64 * 136];
    __shared__ __bf16 Ks[64 * 136];
    __shared__ __bf16 VT[128 * 64];
    __shared__ __bf16 Ps[2][64 * 72];
    __shared__ float rcumf[2][64], qscf[2][64], mkf[64];

    int tid = threadIdx.x;
    int c = blockIdx.x, bh = blockIdx.y;
    int b = bh >> 3, h = bh & 7;
    size_t rowb = (size_t)b * T_DIM + c * LCH;

    if (tid < 128) {
        int s = tid & 63, kk = tid >> 6;
        size_t row = rowb + s;
        int mk = mask[row];
        float bt = mk ? beta[row * 16 + h * 2 + kk] : 1.f;
        float cum = bt;
        #pragma unroll
        for (int off = 1; off < 64; off <<= 1) {
            float p = __shfl(cum, (s >= off) ? s - off : 0);
            if (s >= off) cum *= p;
        }
        rcumf[kk][s] = 1.f / cum;
        qscf[kk][s] = cum * (mk ? mixp[row * 16 + h * 2 + kk] : 0.f);
        if (kk == 0) mkf[s] = mk ? 1.f : 0.f;
    }
    __syncthreads();

    // stage raw Q, K rows; masked V^T (swizzled)
    #pragma unroll
    for (int it = 0; it < 4; ++it) {
        int f = tid + it * 256;
        int t = f >> 4, c8 = (f & 15) * 8;
        size_t g = (rowb + t) * C_DIM + h * D_H + c8;
        *(bf16x8*)&Qs[t * 136 + c8] = *(const bf16x8*)(qg + g);
        *(bf16x8*)&Ks[t * 136 + c8] = *(const bf16x8*)(kg + g);
    }
    #pragma unroll
    for (int it = 0; it < 4; ++it) {
        int f = tid + it * 256;
        int s = f >> 4, c8 = (f & 15) * 8;
        size_t g = (rowb + s) * C_DIM + h * D_H + c8;
        bf16x8 vv = *(const bf16x8*)(vg + g);
        float mf = mkf[s];
        #pragma unroll
        for (int j = 0; j < 8; ++j) {
            int e = c8 + j;
            VT[e * 64 + (s ^ SWE(e))] = (__bf16)(mf * (float)vv[j]);
        }
    }
    __syncthreads();

    int w = tid >> 6, l = tid & 63;
    int lr = l & 15, lg = l >> 4;

    bf16x8 aQ[4];
    #pragma unroll
    for (int kt = 0; kt < 4; ++kt)
        aQ[kt] = *(const bf16x8*)&Qs[(w * 16 + lr) * 136 + kt * 32 + lg * 8];

    // Praw = q K^T (kk-independent), wave-local t-rows in registers
    f32x4 Praw[4];
    #pragma unroll
    for (int st = 0; st < 4; ++st) {
        f32x4 p = {};
        #pragma unroll
        for (int kt = 0; kt < 4; ++kt) {
            bf16x8 bk = *(const bf16x8*)&Ks[(st * 16 + lr) * 136 + kt * 32 + lg * 8];
            p = __builtin_amdgcn_mfma_f32_16x16x32_bf16(aQ[kt], bk, p, 0, 0, 0);
        }
        Praw[st] = p;
    }

    f32x4 yA[8] = {};
    #pragma unroll
    for (int kk = 0; kk < 2; ++kk) {
        // scaled causal P -> Ps[kk] (wave-local rows; no barrier needed)
        #pragma unroll
        for (int st = 0; st < 4; ++st) {
            #pragma unroll
            for (int r = 0; r < 4; ++r) {
                int tl = w * 16 + lg * 4 + r;
                int sc = st * 16 + lr;
                float pv = (sc <= tl) ? Praw[st][r] * rcumf[kk][sc] * qscf[kk][tl] : 0.f;
                Ps[kk][tl * 72 + sc] = (__bf16)pv;
            }
        }
        bf16x8 aP[2];
        #pragma unroll
        for (int k2 = 0; k2 < 2; ++k2)
            aP[k2] = *(const bf16x8*)&Ps[kk][(w * 16 + lr) * 72 + k2 * 32 + lg * 8];

        const __bf16* stb = ST + ((size_t)(bh * 2 + kk) * NCH + c) * CHSZ;
        #pragma unroll
        for (int et = 0; et < 8; ++et) {
            int e = et * 16 + lr;
            f32x4 ys = {};
            #pragma unroll
            for (int kt = 0; kt < 4; ++kt) {
                bf16x8 bs = *(const bf16x8*)(stb + e * 128 + kt * 32 + lg * 8);
                ys = __builtin_amdgcn_mfma_f32_16x16x32_bf16(aQ[kt], bs, ys, 0, 0, 0);
            }
            f32x4 yp = {};
            #pragma unroll
            for (int k2 = 0; k2 < 2; ++k2) {
                bf16x8 bv = *(const bf16x8*)&VT[e * 64 + ((k2 * 32 + lg * 8) ^ SWE(e))];
                yp = __builtin_amdgcn_mfma_f32_16x16x32_bf16(aP[k2], bv, yp, 0, 0, 0);
            }
            #pragma unroll
            for (int r = 0; r < 4; ++r)
                yA[et][r] += ys[r] * qscf[kk][w * 16 + lg * 4 + r] + yp[r];
        }
    }
    #pragma unroll
    for (int et = 0; et < 8; ++et)
        #pragma unroll
        for (int r = 0; r < 4; ++r) {
            size_t row = rowb + w * 16 + lg * 4 + r;
            yg[row * C_DIM + h * D_H + et * 16 + lr] = (__bf16)yA[et][r];
        }
}

extern "C" void kernel_launch(void* const* d_in, const int* in_sizes, int n_in,
                              void* d_out, int out_size, void* d_ws, size_t ws_size,
                              hipStream_t stream) {
    const float* x    = (const float*)d_in[0];
    const int*   mask = (const int*)d_in[1];
    const float* Wq   = (const float*)d_in[2];
    const float* Wk   = (const float*)d_in[3];
    const float* Wv   = (const float*)d_in[4];
    const float* Wb   = (const float*)d_in[5];
    const float* bb   = (const float*)d_in[6];
    const float* Wm   = (const float*)d_in[7];
    const float* bm   = (const float*)d_in[8];
    const float* Wo   = (const float*)d_in[9];
    const float* bo   = (const float*)d_in[10];
    float* out = (float*)d_out;

    __bf16* q    = (__bf16*)d_ws;                 // MC
    __bf16* k    = q + MC;                        // MC
    __bf16* v    = k + MC;                        // MC
    __bf16* xb   = v + MC;                        // MC; reused as ysum after GEMMs
    __bf16* WT   = xb + MC;                       // 4 * C*C
    __bf16* BT   = WT + (size_t)4 * C_DIM * C_DIM;// 64*NCH*CHSZ
    float* beta  = (float*)(BT + (size_t)64 * NCH * CHSZ);
    float* mixb  = beta + M_ROWS * 16;
    float* cumL  = mixb + M_ROWS * 16;
    float2* rope = (float2*)(cumL + 64 * NCH);
    __bf16* ysum = xb;

    rope_table_k<<<dim3((T_DIM * 64) / 256), dim3(256), 0, stream>>>(rope);
    betamix_k<<<dim3(M_ROWS / 8), dim3(256), 0, stream>>>(x, Wb, bb, Wm, bm, beta, mixb);
    cvt_x_k<<<dim3(MC / 8 / 256), dim3(256), 0, stream>>>(x, xb);
    wtrans_k<<<dim3(16, 16, 4), dim3(256), 0, stream>>>(Wq, Wk, Wv, Wo, WT);

    const size_t CC = (size_t)C_DIM * C_DIM;
    dim3 ggrid((M_ROWS / 128) * (C_DIM / 128));
    gemm_bt<true,  false><<<ggrid, dim3(256), 0, stream>>>(xb, WT,          q,   M_ROWS, C_DIM, C_DIM, rope, nullptr);
    gemm_bt<true,  false><<<ggrid, dim3(256), 0, stream>>>(xb, WT + CC,     k,   M_ROWS, C_DIM, C_DIM, rope, nullptr);
    gemm_bt<false, false><<<ggrid, dim3(256), 0, stream>>>(xb, WT + 2 * CC, v,   M_ROWS, C_DIM, C_DIM, nullptr, nullptr);

    chunk_sum_k<<<dim3(NCH, 2, 32), dim3(256), 0, stream>>>(k, v, beta, mask, BT, cumL);
    chunk_scan_k<<<dim3(512), dim3(256), 0, stream>>>(BT, cumL);
    chunk_out_k<<<dim3(NCH, 32), dim3(256), 0, stream>>>(q, k, v, BT, beta, mixb, mask, ysum);

    gemm_bt<false, true><<<ggrid, dim3(256), 0, stream>>>(ysum, WT + 3 * CC, out, M_ROWS, C_DIM, C_DIM, nullptr, bo);
}

// Round 7
// 245.892 us; speedup vs baseline: 3.7869x; 1.2186x over previous
//
#include <hip/hip_runtime.h>

typedef __attribute__((ext_vector_type(4))) float f32x4;
typedef __attribute__((ext_vector_type(8))) __bf16 bf16x8;

#define T_DIM 2048
#define B_DIM 4
#define C_DIM 1024
#define H_N 8
#define D_H 128
#define M_ROWS 8192   // B*T
#define MC ((size_t)M_ROWS * C_DIM)
#define LCH 64               // chunk length
#define NCH (T_DIM / LCH)    // 32 chunks
#define CHSZ (128 * 128)     // state tile elements
// XOR swizzle (element col, 8-wide blocks) for transposed [r][64] bf16 tiles
#define SWE(r) ((((r) ^ ((r) >> 3)) & 7) << 3)

#define GLDS16(g, l) __builtin_amdgcn_global_load_lds( \
    (const __attribute__((address_space(1))) void*)(g), \
    (__attribute__((address_space(3))) void*)(l), 16, 0, 0)

// ---------------- RoPE cos/sin table ----------------
__global__ void rope_table_k(float2* __restrict__ tab) {
    int idx = blockIdx.x * 256 + threadIdx.x;
    if (idx >= T_DIM * 64) return;
    int t = idx >> 6, i = idx & 63;
    float freq = expf(-(2.0f * (float)i / 128.0f) * 9.210340371976184f);
    float a = (float)t * freq;
    tab[idx] = make_float2(cosf(a), sinf(a));
}

// ---------------- x -> bf16 ----------------
__global__ __launch_bounds__(256) void cvt_x_k(const float* __restrict__ in,
                                               __bf16* __restrict__ out) {
    int i = blockIdx.x * 256 + threadIdx.x;   // one 8-elem chunk each
    f32x4 a = ((const f32x4*)in)[i * 2];
    f32x4 b = ((const f32x4*)in)[i * 2 + 1];
    bf16x8 o;
    o[0] = (__bf16)a.x; o[1] = (__bf16)a.y; o[2] = (__bf16)a.z; o[3] = (__bf16)a.w;
    o[4] = (__bf16)b.x; o[5] = (__bf16)b.y; o[6] = (__bf16)b.z; o[7] = (__bf16)b.w;
    ((bf16x8*)out)[i] = o;
}

// ---------------- weight transpose+convert: W[K][N] f32 -> WT[N][K] bf16 ----
__global__ __launch_bounds__(256) void wtrans_k(
    const float* __restrict__ W0, const float* __restrict__ W1,
    const float* __restrict__ W2, const float* __restrict__ W3,
    __bf16* __restrict__ out) {
    const float* W = blockIdx.z == 0 ? W0 : blockIdx.z == 1 ? W1 :
                     blockIdx.z == 2 ? W2 : W3;
    __bf16* o = out + (size_t)blockIdx.z * C_DIM * C_DIM;
    __shared__ float t[64][65];
    int tid = threadIdx.x;
    int r0 = blockIdx.y * 64, c0 = blockIdx.x * 64;
    #pragma unroll
    for (int it = 0; it < 4; ++it) {
        int idx = it * 256 + tid;
        int r = idx >> 4, c4 = (idx & 15) * 4;
        f32x4 v = *(const f32x4*)(W + (size_t)(r0 + r) * C_DIM + c0 + c4);
        t[r][c4] = v.x; t[r][c4 + 1] = v.y; t[r][c4 + 2] = v.z; t[r][c4 + 3] = v.w;
    }
    __syncthreads();
    #pragma unroll
    for (int it = 0; it < 2; ++it) {
        int idx = it * 256 + tid;
        int n = idx >> 3, k8 = (idx & 7) * 8;
        bf16x8 ov;
        #pragma unroll
        for (int j = 0; j < 8; ++j) ov[j] = (__bf16)t[k8 + j][n];
        *(bf16x8*)(o + (size_t)(c0 + n) * C_DIM + r0 + k8) = ov;
    }
}

// ---------------- Wb/Wm [1024][16] f32 -> WbmT [32][1024] bf16 ----------
__global__ __launch_bounds__(256) void wbm_trans_k(
    const float* __restrict__ Wb, const float* __restrict__ Wm,
    __bf16* __restrict__ WbmT) {
    int n = blockIdx.x;              // 0..31
    int col = n & 15;
    const float* W = (n < 16) ? Wb : Wm;
    for (int k = threadIdx.x; k < C_DIM; k += 256)
        WbmT[(size_t)n * C_DIM + k] = (__bf16)W[(size_t)k * 16 + col];
}

// ---------------- beta/mix via MFMA: logits = xb @ WbmT^T + bias -------
// grid 256 blocks x 256 thr; block = 32 rows; wave w: row-frag (w>>1), col-frag (w&1).
// j=0 -> sigmoid -> beta ; j=1 -> pairwise softmax -> mix.
__global__ __launch_bounds__(256) void betamix_mfma(
    const __bf16* __restrict__ xb, const __bf16* __restrict__ WbmT,
    const float* __restrict__ bb, const float* __restrict__ bm,
    float* __restrict__ beta, float* __restrict__ mix) {
    __shared__ __bf16 As[32 * 64];   // 4 KB

    int tid = threadIdx.x;
    int w = tid >> 6, lane = tid & 63;
    int lr = lane & 15, lg = lane >> 4;
    int ifr = w >> 1, j = w & 1;
    int rows0 = blockIdx.x * 32;

    // staging map: granule tid -> row=tid>>3, g=(tid&7)^(row&7)
    int srow = tid >> 3;
    int sg = (tid & 7) ^ (srow & 7);
    size_t aoff = (size_t)(rows0 + srow) * C_DIM + sg * 8;
    char* ldsb = (char*)As + w * 64 * 16;   // wave-uniform base

    f32x4 acc = {};
    const __bf16* Wrow = WbmT + (size_t)(j * 16 + lr) * C_DIM;

    for (int k0 = 0; k0 < C_DIM; k0 += 64) {
        __syncthreads();
        GLDS16(xb + aoff + k0, ldsb);
        __syncthreads();
        #pragma unroll
        for (int ss = 0; ss < 2; ++ss) {
            int ar = ifr * 16 + lr;
            bf16x8 af = *(const bf16x8*)((char*)As + ar * 128 + (((ss * 4 + lg) ^ (ar & 7)) << 4));
            bf16x8 bf = *(const bf16x8*)(Wrow + k0 + ss * 32 + lg * 8);
            acc = __builtin_amdgcn_mfma_f32_16x16x32_bf16(af, bf, acc, 0, 0, 0);
        }
    }

    float bias = (j ? bm : bb)[lr];
    #pragma unroll
    for (int r = 0; r < 4; ++r) {
        int row = rows0 + ifr * 16 + lg * 4 + r;
        float v = acc[r] + bias;
        if (j == 0) {
            beta[(size_t)row * 16 + lr] = 1.f / (1.f + expf(-v));
        } else {
            float other = __shfl_xor(v, 1);
            float mx = fmaxf(v, other);
            float e = expf(v - mx), eo = expf(other - mx);
            mix[(size_t)row * 16 + lr] = e / (e + eo);
        }
    }
}

// ---------------- bf16 GEMM, m97 structure + XCD swizzle ----------------
template<bool ROPE, bool OUTF32>
__global__ __launch_bounds__(256) void gemm_bt(
    const __bf16* __restrict__ A, const __bf16* __restrict__ BT,
    void* __restrict__ Cp, int M, int N, int K,
    const float2* __restrict__ rope_tab, const float* __restrict__ bias) {
    __shared__ __bf16 As[128 * 64];
    __shared__ __bf16 Bs[128 * 64];

    int tid = threadIdx.x;
    int nTN = N >> 7;
    // XCD-aware swizzle (gridDim.x % 8 == 0 by construction)
    int cpx = gridDim.x >> 3;
    int bid = ((int)blockIdx.x & 7) * cpx + ((int)blockIdx.x >> 3);
    int bm = bid / nTN, bn = bid % nTN;
    int m_base = bm << 7, n_base = bn << 7;
    int w = tid >> 6, lane = tid & 63;
    int lr = lane & 15, lg = lane >> 4;
    int wm = (w >> 1) * 64, wn = (w & 1) * 64;

    // per-lane pre-swizzled global offsets + wave-uniform LDS bases
    size_t aoff[4], boff[4];
    int ldso[4];
    #pragma unroll
    for (int it = 0; it < 4; ++it) {
        int gi = it * 256 + tid;
        int row = gi >> 3;
        int g = (gi & 7) ^ (row & 7);
        aoff[it] = (size_t)(m_base + row) * K + g * 8;
        boff[it] = (size_t)(n_base + row) * K + g * 8;
        ldso[it] = (it * 256 + w * 64) * 16;   // bytes, wave-uniform
    }

    f32x4 acc[4][4] = {};

    for (int k0 = 0; k0 < K; k0 += 64) {
        __syncthreads();
        #pragma unroll
        for (int it = 0; it < 4; ++it) {
            GLDS16(A + aoff[it] + k0, (char*)As + ldso[it]);
            GLDS16(BT + boff[it] + k0, (char*)Bs + ldso[it]);
        }
        __syncthreads();
        #pragma unroll
        for (int ss = 0; ss < 2; ++ss) {
            bf16x8 af[4], bfr[4];
            #pragma unroll
            for (int i = 0; i < 4; ++i) {
                int ar = wm + i * 16 + lr;
                af[i] = *(const bf16x8*)((char*)As + ar * 128 + (((ss * 4 + lg) ^ (ar & 7)) << 4));
                int br = wn + i * 16 + lr;
                bfr[i] = *(const bf16x8*)((char*)Bs + br * 128 + (((ss * 4 + lg) ^ (br & 7)) << 4));
            }
            #pragma unroll
            for (int i = 0; i < 4; ++i)
                #pragma unroll
                for (int j = 0; j < 4; ++j)
                    acc[i][j] = __builtin_amdgcn_mfma_f32_16x16x32_bf16(af[i], bfr[j], acc[i][j], 0, 0, 0);
        }
    }

    #pragma unroll
    for (int i = 0; i < 4; ++i) {
        #pragma unroll
        for (int j = 0; j < 4; ++j) {
            #pragma unroll
            for (int r = 0; r < 4; ++r) {
                int grow = m_base + wm + i * 16 + (lg << 2) + r;
                int gcol = n_base + wn + j * 16 + lr;
                float val = acc[i][j][r];
                if (ROPE) {
                    float partner = __shfl_xor(val, 1);
                    int t = grow & (T_DIM - 1);
                    int ii = (gcol & 127) >> 1;
                    float2 cs = rope_tab[t * 64 + ii];
                    val = (gcol & 1) ? (partner * cs.y + val * cs.x)
                                     : (val * cs.x - partner * cs.y);
                }
                if (bias) val += bias[gcol];
                size_t idx = (size_t)grow * N + gcol;
                if (OUTF32) ((float*)Cp)[idx] = val;
                else        ((__bf16*)Cp)[idx] = (__bf16)val;
            }
        }
    }
}

// ============ chunk-parallel scan ============
// Pass A: per-chunk summary  B^T_c[e][d] = sum_s (mf*v)[s][e] * (wv*k)[s][d]
__global__ __launch_bounds__(256) void chunk_sum_k(
    const __bf16* __restrict__ kg, const __bf16* __restrict__ vg,
    const float* __restrict__ beta, const int* __restrict__ mask,
    __bf16* __restrict__ BT, float* __restrict__ cumLg) {
    __shared__ __bf16 KT[128 * 64];
    __shared__ __bf16 VT[128 * 64];
    __shared__ float wvf[LCH], mkf[LCH];

    int tid = threadIdx.x;
    int c = blockIdx.x, kk = blockIdx.y, bh = blockIdx.z;
    int b = bh >> 3, h = bh & 7;
    int scan = bh * 2 + kk;
    size_t rowb = (size_t)b * T_DIM + c * LCH;

    if (tid < 64) {
        int s = tid;
        size_t row = rowb + s;
        int mk = mask[row];
        float mf = mk ? 1.f : 0.f;
        float bt = mk ? beta[row * 16 + h * 2 + kk] : 1.f;
        float cum = bt;
        #pragma unroll
        for (int off = 1; off < 64; off <<= 1) {
            float p = __shfl(cum, (s >= off) ? s - off : 0);
            if (s >= off) cum *= p;
        }
        float cl = __shfl(cum, 63);
        wvf[s] = cl / cum;
        mkf[s] = mf;
        if (s == 63) cumLg[scan * NCH + c] = cum;
    }
    __syncthreads();

    #pragma unroll
    for (int it = 0; it < 4; ++it) {
        int f = tid + it * 256;
        int s = f >> 4, c8 = (f & 15) * 8;
        size_t g = (rowb + s) * C_DIM + h * D_H + c8;
        bf16x8 kv = *(const bf16x8*)(kg + g);
        bf16x8 vv = *(const bf16x8*)(vg + g);
        float ws_ = wvf[s], mf = mkf[s];
        #pragma unroll
        for (int j = 0; j < 8; ++j) {
            int d = c8 + j;
            KT[d * 64 + (s ^ SWE(d))] = (__bf16)(ws_ * (float)kv[j]);
            VT[d * 64 + (s ^ SWE(d))] = (__bf16)(mf * (float)vv[j]);
        }
    }
    __syncthreads();

    int w = tid >> 6, l = tid & 63;
    int lr = l & 15, lg = l >> 4;
    f32x4 acc[2][8] = {};
    #pragma unroll
    for (int kt = 0; kt < 2; ++kt) {
        int col = kt * 32 + lg * 8;
        bf16x8 aV[2], bK[8];
        #pragma unroll
        for (int et = 0; et < 2; ++et) {
            int e = w * 32 + et * 16 + lr;
            aV[et] = *(const bf16x8*)&VT[e * 64 + (col ^ SWE(e))];
        }
        #pragma unroll
        for (int dt = 0; dt < 8; ++dt) {
            int d = dt * 16 + lr;
            bK[dt] = *(const bf16x8*)&KT[d * 64 + (col ^ SWE(d))];
        }
        #pragma unroll
        for (int et = 0; et < 2; ++et)
            #pragma unroll
            for (int dt = 0; dt < 8; ++dt)
                acc[et][dt] = __builtin_amdgcn_mfma_f32_16x16x32_bf16(aV[et], bK[dt], acc[et][dt], 0, 0, 0);
    }

    __bf16* bout = BT + ((size_t)scan * NCH + c) * CHSZ;
    #pragma unroll
    for (int et = 0; et < 2; ++et)
        #pragma unroll
        for (int dt = 0; dt < 8; ++dt)
            #pragma unroll
            for (int r = 0; r < 4; ++r) {
                int e = w * 32 + et * 16 + lg * 4 + r;
                bout[e * 128 + dt * 16 + lr] = (__bf16)acc[et][dt][r];
            }
}

// Pass B: in-place inter-chunk recurrence. BT[c] := S_start(c)
__global__ __launch_bounds__(256) void chunk_scan_k(
    __bf16* __restrict__ BT, const float* __restrict__ cumLg) {
    int bid = blockIdx.x;
    int scan = bid >> 3, part = bid & 7;
    int tid = threadIdx.x;
    int e = part * 16 + (tid >> 4);
    int d0 = (tid & 15) * 8;
    __bf16* base = BT + (size_t)scan * NCH * CHSZ + e * 128 + d0;
    const float* cl = cumLg + scan * NCH;
    float acc[8] = {};
    for (int c = 0; c < NCH; ++c) {
        bf16x8 bv = *(const bf16x8*)(base + (size_t)c * CHSZ);
        float g = cl[c];
        bf16x8 so;
        #pragma unroll
        for (int j = 0; j < 8; ++j) so[j] = (__bf16)acc[j];
        *(bf16x8*)(base + (size_t)c * CHSZ) = so;
        #pragma unroll
        for (int j = 0; j < 8; ++j) acc[j] = g * acc[j] + (float)bv[j];
    }
}

// Pass C (merged kk): Praw = qK^T once; per kk: y += (qsc*rcum*P)@V + qsc*(q@S_kk)
__global__ __launch_bounds__(256) void chunk_out_k(
    const __bf16* __restrict__ qg, const __bf16* __restrict__ kg,
    const __bf16* __restrict__ vg, const __bf16* __restrict__ ST,
    const float* __restrict__ beta, const float* __restrict__ mixp,
    const int* __restrict__ mask, __bf16* __restrict__ yg) {
    __shared__ __bf16 Qs[64 * 136];
    __shared__ __bf16 Ks[64 * 136];
    __shared__ __bf16 VT[128 * 64];
    __shared__ __bf16 Ps[2][64 * 72];
    __shared__ float rcumf[2][64], qscf[2][64], mkf[64];

    int tid = threadIdx.x;
    int c = blockIdx.x, bh = blockIdx.y;
    int b = bh >> 3, h = bh & 7;
    size_t rowb = (size_t)b * T_DIM + c * LCH;

    if (tid < 128) {
        int s = tid & 63, kk = tid >> 6;
        size_t row = rowb + s;
        int mk = mask[row];
        float bt = mk ? beta[row * 16 + h * 2 + kk] : 1.f;
        float cum = bt;
        #pragma unroll
        for (int off = 1; off < 64; off <<= 1) {
            float p = __shfl(cum, (s >= off) ? s - off : 0);
            if (s >= off) cum *= p;
        }
        rcumf[kk][s] = 1.f / cum;
        qscf[kk][s] = cum * (mk ? mixp[row * 16 + h * 2 + kk] : 0.f);
        if (kk == 0) mkf[s] = mk ? 1.f : 0.f;
    }
    __syncthreads();

    #pragma unroll
    for (int it = 0; it < 4; ++it) {
        int f = tid + it * 256;
        int t = f >> 4, c8 = (f & 15) * 8;
        size_t g = (rowb + t) * C_DIM + h * D_H + c8;
        *(bf16x8*)&Qs[t * 136 + c8] = *(const bf16x8*)(qg + g);
        *(bf16x8*)&Ks[t * 136 + c8] = *(const bf16x8*)(kg + g);
    }
    #pragma unroll
    for (int it = 0; it < 4; ++it) {
        int f = tid + it * 256;
        int s = f >> 4, c8 = (f & 15) * 8;
        size_t g = (rowb + s) * C_DIM + h * D_H + c8;
        bf16x8 vv = *(const bf16x8*)(vg + g);
        float mf = mkf[s];
        #pragma unroll
        for (int j = 0; j < 8; ++j) {
            int e = c8 + j;
            VT[e * 64 + (s ^ SWE(e))] = (__bf16)(mf * (float)vv[j]);
        }
    }
    __syncthreads();

    int w = tid >> 6, l = tid & 63;
    int lr = l & 15, lg = l >> 4;

    bf16x8 aQ[4];
    #pragma unroll
    for (int kt = 0; kt < 4; ++kt)
        aQ[kt] = *(const bf16x8*)&Qs[(w * 16 + lr) * 136 + kt * 32 + lg * 8];

    f32x4 Praw[4];
    #pragma unroll
    for (int st = 0; st < 4; ++st) {
        f32x4 p = {};
        #pragma unroll
        for (int kt = 0; kt < 4; ++kt) {
            bf16x8 bk = *(const bf16x8*)&Ks[(st * 16 + lr) * 136 + kt * 32 + lg * 8];
            p = __builtin_amdgcn_mfma_f32_16x16x32_bf16(aQ[kt], bk, p, 0, 0, 0);
        }
        Praw[st] = p;
    }

    f32x4 yA[8] = {};
    #pragma unroll
    for (int kk = 0; kk < 2; ++kk) {
        #pragma unroll
        for (int st = 0; st < 4; ++st) {
            #pragma unroll
            for (int r = 0; r < 4; ++r) {
                int tl = w * 16 + lg * 4 + r;
                int sc = st * 16 + lr;
                float pv = (sc <= tl) ? Praw[st][r] * rcumf[kk][sc] * qscf[kk][tl] : 0.f;
                Ps[kk][tl * 72 + sc] = (__bf16)pv;
            }
        }
        bf16x8 aP[2];
        #pragma unroll
        for (int k2 = 0; k2 < 2; ++k2)
            aP[k2] = *(const bf16x8*)&Ps[kk][(w * 16 + lr) * 72 + k2 * 32 + lg * 8];

        const __bf16* stb = ST + ((size_t)(bh * 2 + kk) * NCH + c) * CHSZ;
        #pragma unroll
        for (int et = 0; et < 8; ++et) {
            int e = et * 16 + lr;
            f32x4 ys = {};
            #pragma unroll
            for (int kt = 0; kt < 4; ++kt) {
                bf16x8 bs = *(const bf16x8*)(stb + e * 128 + kt * 32 + lg * 8);
                ys = __builtin_amdgcn_mfma_f32_16x16x32_bf16(aQ[kt], bs, ys, 0, 0, 0);
            }
            f32x4 yp = {};
            #pragma unroll
            for (int k2 = 0; k2 < 2; ++k2) {
                bf16x8 bv = *(const bf16x8*)&VT[e * 64 + ((k2 * 32 + lg * 8) ^ SWE(e))];
                yp = __builtin_amdgcn_mfma_f32_16x16x32_bf16(aP[k2], bv, yp, 0, 0, 0);
            }
            #pragma unroll
            for (int r = 0; r < 4; ++r)
                yA[et][r] += ys[r] * qscf[kk][w * 16 + lg * 4 + r] + yp[r];
        }
    }
    #pragma unroll
    for (int et = 0; et < 8; ++et)
        #pragma unroll
        for (int r = 0; r < 4; ++r) {
            size_t row = rowb + w * 16 + lg * 4 + r;
            yg[row * C_DIM + h * D_H + et * 16 + lr] = (__bf16)yA[et][r];
        }
}

extern "C" void kernel_launch(void* const* d_in, const int* in_sizes, int n_in,
                              void* d_out, int out_size, void* d_ws, size_t ws_size,
                              hipStream_t stream) {
    const float* x    = (const float*)d_in[0];
    const int*   mask = (const int*)d_in[1];
    const float* Wq   = (const float*)d_in[2];
    const float* Wk   = (const float*)d_in[3];
    const float* Wv   = (const float*)d_in[4];
    const float* Wb   = (const float*)d_in[5];
    const float* bb   = (const float*)d_in[6];
    const float* Wm   = (const float*)d_in[7];
    const float* bm   = (const float*)d_in[8];
    const float* Wo   = (const float*)d_in[9];
    const float* bo   = (const float*)d_in[10];
    float* out = (float*)d_out;

    __bf16* q    = (__bf16*)d_ws;                 // MC
    __bf16* k    = q + MC;                        // MC
    __bf16* v    = k + MC;                        // MC
    __bf16* xb   = v + MC;                        // MC; reused as ysum after GEMMs
    __bf16* WT   = xb + MC;                       // 4 * C*C
    __bf16* BT   = WT + (size_t)4 * C_DIM * C_DIM;// 64*NCH*CHSZ
    float* beta  = (float*)(BT + (size_t)64 * NCH * CHSZ);
    float* mixb  = beta + M_ROWS * 16;
    float* cumL  = mixb + M_ROWS * 16;
    float2* rope = (float2*)(cumL + 64 * NCH);
    __bf16* WbmT = (__bf16*)(rope + T_DIM * 64);  // 32*1024
    __bf16* ysum = xb;

    rope_table_k<<<dim3((T_DIM * 64) / 256), dim3(256), 0, stream>>>(rope);
    cvt_x_k<<<dim3(MC / 8 / 256), dim3(256), 0, stream>>>(x, xb);
    wtrans_k<<<dim3(16, 16, 4), dim3(256), 0, stream>>>(Wq, Wk, Wv, Wo, WT);
    wbm_trans_k<<<dim3(32), dim3(256), 0, stream>>>(Wb, Wm, WbmT);
    betamix_mfma<<<dim3(M_ROWS / 32), dim3(256), 0, stream>>>(xb, WbmT, bb, bm, beta, mixb);

    const size_t CC = (size_t)C_DIM * C_DIM;
    dim3 ggrid((M_ROWS / 128) * (C_DIM / 128));
    gemm_bt<true,  false><<<ggrid, dim3(256), 0, stream>>>(xb, WT,          q,   M_ROWS, C_DIM, C_DIM, rope, nullptr);
    gemm_bt<true,  false><<<ggrid, dim3(256), 0, stream>>>(xb, WT + CC,     k,   M_ROWS, C_DIM, C_DIM, rope, nullptr);
    gemm_bt<false, false><<<ggrid, dim3(256), 0, stream>>>(xb, WT + 2 * CC, v,   M_ROWS, C_DIM, C_DIM, nullptr, nullptr);

    chunk_sum_k<<<dim3(NCH, 2, 32), dim3(256), 0, stream>>>(k, v, beta, mask, BT, cumL);
    chunk_scan_k<<<dim3(512), dim3(256), 0, stream>>>(BT, cumL);
    chunk_out_k<<<dim3(NCH, 32), dim3(256), 0, stream>>>(q, k, v, BT, beta, mixb, mask, ysum);

    gemm_bt<false, true><<<ggrid, dim3(256), 0, stream>>>(ysum, WT + 3 * CC, out, M_ROWS, C_DIM, C_DIM, nullptr, bo);
}